// Round 13
// baseline (1378.503 us; speedup 1.0000x reference)
//
#include <hip/hip_runtime.h>
#include <hip/hip_bf16.h>

using bf16 = __hip_bfloat16;
typedef __attribute__((ext_vector_type(8))) short short8;  // 8 bf16 (4 VGPRs)
typedef __attribute__((ext_vector_type(4))) float f32x4;   // MFMA C/D
typedef __attribute__((ext_vector_type(4))) int   iv4;     // 16B of packed bf16

static constexpr int NN = 100000;   // nodes
static constexpr int NE = 1600000;  // message edges
static constexpr int NS = 500000;   // scored edges
static constexpr int HH = 64;       // hidden
static constexpr int SCAN_B = 1024;
static constexpr int SCAN_G = (NN + SCAN_B - 1) / SCAN_B;   // 98
static constexpr int DPW = 4;       // dsts per group (finer units for queue balance)
static constexpr int NGRP = (NN + DPW - 1) / DPW;           // 25000

__device__ __forceinline__ float b2f(bf16 v) { return __bfloat162float(v); }
__device__ __forceinline__ float bflo(int u)  { return __uint_as_float(((unsigned)u) << 16); }
__device__ __forceinline__ float bfhi(int u)  { return __uint_as_float(((unsigned)u) & 0xffff0000u); }
__device__ __forceinline__ int pk2(float a, float b) {
    unsigned lo = __bfloat16_as_ushort(__float2bfloat16(a));
    unsigned hi = __bfloat16_as_ushort(__float2bfloat16(b));
    return (int)(lo | (hi << 16));
}
__device__ __forceinline__ int bcasti(int v, int k) {
    return __builtin_amdgcn_readlane(v, k);
}

// ---------------- weight prep ----------------

__global__ void prep_k(const float* __restrict__ We, const float* __restrict__ be,
                       const float* __restrict__ C0, const float* __restrict__ cb0,
                       float* __restrict__ We0, float* __restrict__ bb0) {
    int j = threadIdx.x;
    if (j >= HH) return;
    float s0 = 0.f, s1 = 0.f, sb = 0.f;
    for (int k = 0; k < HH; ++k) {
        float c = C0[k * HH + j];
        s0 = fmaf(We[k], c, s0);
        s1 = fmaf(We[HH + k], c, s1);
        sb = fmaf(be[k], c, sb);
    }
    We0[j] = s0; We0[HH + j] = s1; bb0[j] = sb + cb0[j];
}

// ---------------- CSR build ----------------

__global__ void zero_int_k(int* __restrict__ p, int n) {
    int i = blockIdx.x * blockDim.x + threadIdx.x;
    if (i < n) p[i] = 0;
}

__global__ void hist_k(const int* __restrict__ dst, int* __restrict__ cnt) {
    int i = blockIdx.x * blockDim.x + threadIdx.x;
    if (i < NE) atomicAdd(&cnt[dst[i]], 1);
}

__global__ void scan1_k(const int* __restrict__ cnt, int* __restrict__ rowptr,
                        int* __restrict__ bsum) {
    __shared__ int sm[SCAN_B];
    int t = threadIdx.x, idx = blockIdx.x * SCAN_B + t;
    int v = (idx < NN) ? cnt[idx] : 0;
    sm[t] = v;
    __syncthreads();
    for (int off = 1; off < SCAN_B; off <<= 1) {
        int add = (t >= off) ? sm[t - off] : 0;
        __syncthreads();
        sm[t] += add;
        __syncthreads();
    }
    if (idx < NN) rowptr[idx] = sm[t] - v;
    if (t == SCAN_B - 1) bsum[blockIdx.x] = sm[t];
}

__global__ void scan2_k(const int* __restrict__ bsum, int* __restrict__ bofs) {
    if (threadIdx.x == 0) {
        int acc = 0;
        for (int b = 0; b < SCAN_G; ++b) { bofs[b] = acc; acc += bsum[b]; }
    }
}

__global__ void scan3_k(int* __restrict__ rowptr, int* __restrict__ cursor,
                        const int* __restrict__ bofs) {
    int idx = blockIdx.x * SCAN_B + threadIdx.x;
    if (idx < NN) {
        int r = rowptr[idx] + bofs[blockIdx.x];
        rowptr[idx] = r;
        cursor[idx] = r;
    }
    if (idx == 0) rowptr[NN] = NE;
}

__global__ void scatter_k(const int* __restrict__ dst, const int* __restrict__ src,
                          const float2* __restrict__ e0, int* __restrict__ cursor,
                          int4* __restrict__ sedge) {
    int i = blockIdx.x * blockDim.x + threadIdx.x;
    if (i < NE) {
        int p = atomicAdd(&cursor[dst[i]], 1);
        float2 ev = e0[i];
        sedge[p] = make_int4(src[i], __float_as_int(ev.x), __float_as_int(ev.y), 0);
    }
}

// ---------------- MFMA node transforms: out = h @ W for (A,B) / (V,U) ----------------
// FIRST: h row computed on the fly from x@Wn+bn (layer 0 — no encode kernel).
template <bool FIRST>
__global__ __launch_bounds__(256, 2)
void transform_mfma_k(const float* __restrict__ h, const float* __restrict__ x,
                      const float* __restrict__ Wn, const float* __restrict__ bn,
                      const float* __restrict__ A, const float* __restrict__ B,
                      const float* __restrict__ V, const float* __restrict__ U,
                      bf16* __restrict__ oA, bf16* __restrict__ oB,
                      bf16* __restrict__ oV, bf16* __restrict__ oU) {
    __shared__ __align__(16) char lds_all[4 * 2048];
    char* lds = lds_all + (threadIdx.x >> 6) * 2048;
    const int lane = threadIdx.x & 63;
    const int l15 = lane & 15, lg = lane >> 4, kb = lg * 8;
    const float *W0, *W1; bf16 *o0, *o1;
    if (blockIdx.y == 0) { W0 = A; W1 = B; o0 = oA; o1 = oB; }
    else                 { W0 = V; W1 = U; o0 = oV; o1 = oU; }

    short8 wf[2][4][2];
#pragma unroll
    for (int m = 0; m < 2; ++m) {
        const float* W = m ? W1 : W0;
#pragma unroll
        for (int t = 0; t < 4; ++t)
#pragma unroll
            for (int f = 0; f < 2; ++f) {
                iv4 q;
#pragma unroll
                for (int j = 0; j < 4; ++j)
                    q[j] = pk2(W[(f * 32 + kb + 2 * j) * HH + t * 16 + l15],
                               W[(f * 32 + kb + 2 * j + 1) * HH + t * 16 + l15]);
                __builtin_memcpy(&wf[m][t][f], &q, 16);
            }
    }
    const int sw = (l15 & 7) << 4;
    int wave = blockIdx.x * 4 + (threadIdx.x >> 6);
    int nw = gridDim.x * 4;
    for (int tile = wave; tile < NN / 16; tile += nw) {
        int row0 = tile * 16;
        iv4 pa, pb;
        if constexpr (FIRST) {
            float2 xv = *(const float2*)(x + 2 * (size_t)(row0 + l15));
#pragma unroll
            for (int j = 0; j < 4; ++j) {
                int k0 = kb + 2 * j;
                pa[j] = pk2(fmaf(xv.x, Wn[k0],     fmaf(xv.y, Wn[HH + k0],     bn[k0])),
                            fmaf(xv.x, Wn[k0 + 1], fmaf(xv.y, Wn[HH + k0 + 1], bn[k0 + 1])));
                int k1 = 32 + kb + 2 * j;
                pb[j] = pk2(fmaf(xv.x, Wn[k1],     fmaf(xv.y, Wn[HH + k1],     bn[k1])),
                            fmaf(xv.x, Wn[k1 + 1], fmaf(xv.y, Wn[HH + k1 + 1], bn[k1 + 1])));
            }
        } else {
            const float* hr = h + (size_t)(row0 + l15) * HH + kb;
            float4 v0 = *(const float4*)(hr);
            float4 v1 = *(const float4*)(hr + 4);
            float4 v2 = *(const float4*)(hr + 32);
            float4 v3 = *(const float4*)(hr + 36);
            pa[0] = pk2(v0.x, v0.y); pa[1] = pk2(v0.z, v0.w);
            pa[2] = pk2(v1.x, v1.y); pa[3] = pk2(v1.z, v1.w);
            pb[0] = pk2(v2.x, v2.y); pb[1] = pk2(v2.z, v2.w);
            pb[2] = pk2(v3.x, v3.y); pb[3] = pk2(v3.z, v3.w);
        }
        short8 af0, af1;
        __builtin_memcpy(&af0, &pa, 16);
        __builtin_memcpy(&af1, &pb, 16);
#pragma unroll
        for (int m = 0; m < 2; ++m) {
            f32x4 acc[4];
#pragma unroll
            for (int t = 0; t < 4; ++t) acc[t] = f32x4{0.f, 0.f, 0.f, 0.f};
#pragma unroll
            for (int t = 0; t < 4; ++t) {
                acc[t] = __builtin_amdgcn_mfma_f32_16x16x32_bf16(af0, wf[m][t][0], acc[t], 0, 0, 0);
                acc[t] = __builtin_amdgcn_mfma_f32_16x16x32_bf16(af1, wf[m][t][1], acc[t], 0, 0, 0);
            }
#pragma unroll
            for (int t = 0; t < 4; ++t)
#pragma unroll
                for (int r = 0; r < 4; ++r) {
                    int row = lg * 4 + r;
                    int ad = (row * 128 + (t * 16 + l15) * 2) ^ ((row & 7) << 4);
                    *(unsigned short*)(lds + ad) =
                        __bfloat16_as_ushort(__float2bfloat16(acc[t][r]));
                }
            int base = l15 * 128 + lg * 32;
            iv4 q0, q1;
            __builtin_memcpy(&q0, lds + ((base) ^ sw), 16);
            __builtin_memcpy(&q1, lds + ((base + 16) ^ sw), 16);
            bf16* out = m ? o1 : o0;
            *(iv4*)(out + (size_t)(row0 + l15) * HH + lg * 16) = q0;
            *(iv4*)(out + (size_t)(row0 + l15) * HH + lg * 16 + 8) = q1;
        }
    }
}

// ---------------- layer-0 aggregate: lane = 4 feats x 4 edge-slots ----------------
__global__ __launch_bounds__(256, 2)
void agg0_k(float* __restrict__ h, const bf16* __restrict__ tabs,
            const float* __restrict__ We0, const float* __restrict__ bb0,
            const int* __restrict__ rowptr, const int4* __restrict__ sedge,
            int* __restrict__ wq) {
    __shared__ float fl_all[4][128];
    float* fl = fl_all[threadIdx.x >> 6];
    const int lane = threadIdx.x & 63;
    const int l15 = lane & 15, lg = lane >> 4;
    const int f0 = l15 * 4;
    const size_t nb = (size_t)NN * HH;

    float w0f[4], w1f[4], bbf[4];
#pragma unroll
    for (int q = 0; q < 4; ++q) {
        w0f[q] = We0[f0 + q];
        w1f[q] = We0[HH + f0 + q];
        bbf[q] = bb0[f0 + q];
    }

    struct R0 { uint2 a0[4], hv[4]; };
    for (;;) {
        int g0 = 0;
        if (lane == 0) g0 = atomicAdd(wq, 1);
        int g = __builtin_amdgcn_readfirstlane(g0);
        if (g >= NGRP) break;
        int dA = g * DPW;
        int ndst = min(DPW, NN - dA);
        int rpv = rowptr[dA + min(lane, ndst)];

        auto endof = [&](int i2) { return bcasti(rpv, i2 + 1); };
        auto begof = [&](int i2) { return bcasti(rpv, i2); };
        auto ldsed = [&](int i2, int b2) -> int4 {
            int en = endof(i2);
            int idx = b2 + min(l15, en - b2 - 1);
            return sedge[idx];
        };
        auto ldrows = [&](const int4& sd, R0& R) {
#pragma unroll
            for (int r = 0; r < 4; ++r) {
                int s = __shfl(sd.x, lg + 4 * r);
                R.a0[r] = *(const uint2*)(tabs + (size_t)s * HH + f0);
                R.hv[r] = *(const uint2*)(tabs + 6 * nb + (size_t)s * HH + f0);
            }
        };
        auto succ = [&](int& i2, int& b2) {
            if (i2 >= ndst) return;
            if (b2 + 16 < endof(i2)) { b2 += 16; return; }
            i2++;
            while (i2 < ndst && endof(i2) <= begof(i2)) i2++;
            if (i2 < ndst) b2 = begof(i2);
        };

        int iC = 0;
        while (iC < ndst && endof(iC) <= begof(iC)) iC++;
        int bC = (iC < ndst) ? begof(iC) : 0;
        int4 sedC = make_int4(0, 0, 0, 0), sedN = sedC;
        R0 rowsC, rowsN;
        if (iC < ndst) sedC = ldsed(iC, bC);
        int iN = iC, bN = bC;
        if (iC < ndst) succ(iN, bN);
        if (iN < ndst) sedN = ldsed(iN, bN);
        if (iC < ndst) ldrows(sedC, rowsC);

        for (int i = 0; i < ndst; ++i) {
            size_t drow = (size_t)(dA + i) * HH;
            float hu = b2f(tabs[7 * nb + drow + lane]);
            float zb[4];
            {
                uint2 bv = *(const uint2*)(tabs + nb + drow + f0);
                zb[0] = bbf[0] + bflo(bv.x); zb[1] = bbf[1] + bfhi(bv.x);
                zb[2] = bbf[2] + bflo(bv.y); zb[3] = bbf[3] + bfhi(bv.y);
            }
            float nm[4] = {0.f, 0.f, 0.f, 0.f}, dn[4] = {0.f, 0.f, 0.f, 0.f};

            while (iC == i) {
                if (iN < ndst) ldrows(sedN, rowsN);
                int iF = iN, bF = bN;
                succ(iF, bF);
                int4 sedF = sedN;
                if (iF < ndst) sedF = ldsed(iF, bF);

                int cnt = min(endof(i) - bC, 16);
#pragma unroll
                for (int r = 0; r < 4; ++r) {
                    int s = lg + 4 * r;
                    bool valid = s < cnt;
                    float ex = __int_as_float(__shfl(sedC.y, s));
                    float ey = __int_as_float(__shfl(sedC.z, s));
                    uint2 a0 = rowsC.a0[r], hv = rowsC.hv[r];
                    float av[4] = {bflo(a0.x), bfhi(a0.x), bflo(a0.y), bfhi(a0.y)};
                    float hvv[4] = {bflo(hv.x), bfhi(hv.x), bflo(hv.y), bfhi(hv.y)};
#pragma unroll
                    for (int q = 0; q < 4; ++q) {
                        float z = fmaf(ex, w0f[q], fmaf(ey, w1f[q], zb[q])) + av[q];
                        float sg = valid ? 1.f / (1.f + __expf(-z)) : 0.f;
                        nm[q] = fmaf(sg, hvv[q], nm[q]);
                        dn[q] += sg;
                    }
                }
                sedC = sedN; rowsC = rowsN; iC = iN; bC = bN;
                iN = iF; bN = bF; sedN = sedF;
            }

#pragma unroll
            for (int m = 16; m < 64; m <<= 1)
#pragma unroll
                for (int q = 0; q < 4; ++q) {
                    nm[q] += __shfl_xor(nm[q], m);
                    dn[q] += __shfl_xor(dn[q], m);
                }
            if (lg == 0) {
#pragma unroll
                for (int q = 0; q < 4; ++q) {
                    fl[f0 + q] = nm[q];
                    fl[64 + f0 + q] = dn[q];
                }
            }
            float nmv = fl[lane], dnv = fl[64 + lane];
            h[drow + lane] = fmaxf(hu + nmv / (dnv + 1e-6f), 0.f);
        }
    }
}

// ---------------- layers 1/2 aggregate ----------------
struct Rows { iv4 ra, rb, hva, hvb, b1a, b1b, b2a, b2b; };

template <int LAYER>
__global__ __launch_bounds__(256, 2)
void agg_k(float* __restrict__ h, const bf16* __restrict__ tabs,
           const float* __restrict__ We0, const float* __restrict__ bb0,
           const float* __restrict__ cb, const float* __restrict__ C,
           const int* __restrict__ rowptr, const int4* __restrict__ sedge,
           int* __restrict__ wq, const float* __restrict__ Wp,
           float* __restrict__ ps, float* __restrict__ pd) {
    __shared__ __align__(16) char cfr[LAYER >= 2 ? 16384 : 8192];
    constexpr int WLDS = (LAYER == 1 ? 4096 : 6144);
    __shared__ __align__(16) char lds_all[4 * WLDS];
    char* lds = lds_all + (threadIdx.x >> 6) * WLDS;
    char* Lb1 = lds;
    char* Lb2 = lds + 2048;
    char* Lhv = lds + (LAYER >= 2 ? 4096 : 2048);
    char* Le1 = lds;
    const int lane = threadIdx.x & 63;
    const int l15 = lane & 15, lg = lane >> 4, kb = lg * 8;
    const size_t nb = (size_t)NN * HH;

    {
        int t = threadIdx.x >> 6;
        const float* C1 = C + 1 * HH * HH;
        const float* C2 = C + 2 * HH * HH;
#pragma unroll
        for (int f = 0; f < 2; ++f) {
            iv4 q;
#pragma unroll
            for (int j = 0; j < 4; ++j)
                q[j] = pk2(C1[(f * 32 + kb + 2 * j) * HH + t * 16 + l15],
                           C1[(f * 32 + kb + 2 * j + 1) * HH + t * 16 + l15]);
            *(iv4*)(cfr + ((t * 2 + f) * 64 + lane) * 16) = q;
            if constexpr (LAYER >= 2) {
                iv4 p;
#pragma unroll
                for (int j = 0; j < 4; ++j)
                    p[j] = pk2(C2[(f * 32 + kb + 2 * j) * HH + t * 16 + l15],
                               C2[(f * 32 + kb + 2 * j + 1) * HH + t * 16 + l15]);
                *(iv4*)(cfr + 8192 + ((t * 2 + f) * 64 + lane) * 16) = p;
            }
        }
        __syncthreads();
    }

    float w0a[8], w0b[8], w1a[8], w1b[8], bba[8], bbb[8];
#pragma unroll
    for (int j = 0; j < 8; ++j) {
        w0a[j] = We0[kb + j];        w0b[j] = We0[32 + kb + j];
        w1a[j] = We0[HH + kb + j];   w1b[j] = We0[HH + 32 + kb + j];
        bba[j] = bb0[kb + j];        bbb[j] = bb0[32 + kb + j];
    }
    float cb1t[4], cb2t[4];
#pragma unroll
    for (int t = 0; t < 4; ++t) cb1t[t] = cb[HH + t * 16 + l15];
    if constexpr (LAYER >= 2) {
#pragma unroll
        for (int t = 0; t < 4; ++t) cb2t[t] = cb[2 * HH + t * 16 + l15];
    }
    float wpa = 0.f, wpb = 0.f;
    if constexpr (LAYER >= 2) { wpa = Wp[lane]; wpb = Wp[HH + lane]; }
    const int wlo = (l15 * 128 + lg * 16) ^ ((l15 & 7) << 4);
    const int whi = (l15 * 128 + 64 + lg * 16) ^ ((l15 & 7) << 4);

    for (;;) {
        int g0 = 0;
        if (lane == 0) g0 = atomicAdd(wq, 1);
        int g = __builtin_amdgcn_readfirstlane(g0);
        if (g >= NGRP) break;
        int dA = g * DPW;
        int ndst = min(DPW, NN - dA);
        int rpv = rowptr[dA + min(lane, ndst)];

        auto endof = [&](int i2) { return bcasti(rpv, i2 + 1); };
        auto begof = [&](int i2) { return bcasti(rpv, i2); };
        auto ldsed = [&](int i2, int b2) -> int4 {
            int en = endof(i2);
            int idx = b2 + min(l15, en - b2 - 1);
            return sedge[idx];
        };
        auto ldrows = [&](const int4& sd, Rows& R) {
            size_t srow = (size_t)sd.x * HH;
            R.ra  = *(const iv4*)(tabs + srow + kb);
            R.rb  = *(const iv4*)(tabs + srow + 32 + kb);
            R.hva = *(const iv4*)(tabs + 6 * nb + srow + kb);
            R.hvb = *(const iv4*)(tabs + 6 * nb + srow + 32 + kb);
            R.b1a = *(const iv4*)(tabs + 2 * nb + srow + kb);
            R.b1b = *(const iv4*)(tabs + 2 * nb + srow + 32 + kb);
            if constexpr (LAYER >= 2) {
                R.b2a = *(const iv4*)(tabs + 4 * nb + srow + kb);
                R.b2b = *(const iv4*)(tabs + 4 * nb + srow + 32 + kb);
            }
        };
        auto succ = [&](int& i2, int& b2) {
            if (i2 >= ndst) return;
            if (b2 + 16 < endof(i2)) { b2 += 16; return; }
            i2++;
            while (i2 < ndst && endof(i2) <= begof(i2)) i2++;
            if (i2 < ndst) b2 = begof(i2);
        };

        int iC = 0;
        while (iC < ndst && endof(iC) <= begof(iC)) iC++;
        int bC = (iC < ndst) ? begof(iC) : 0;
        int4 sedC = make_int4(0, 0, 0, 0), sedN = sedC;
        Rows rowsC, rowsN;
        if (iC < ndst) sedC = ldsed(iC, bC);
        int iN = iC, bN = bC;
        if (iC < ndst) succ(iN, bN);
        if (iN < ndst) sedN = ldsed(iN, bN);
        if (iC < ndst) ldrows(sedC, rowsC);

        for (int i = 0; i < ndst; ++i) {
            size_t drow = (size_t)(dA + i) * HH;
            float hu = b2f(tabs[7 * nb + drow + lane]);
            float zba[8], zbb[8];
            {
                iv4 ba  = *(const iv4*)(tabs + nb + drow + kb);
                iv4 bbv = *(const iv4*)(tabs + nb + drow + 32 + kb);
#pragma unroll
                for (int q = 0; q < 4; ++q) {
                    zba[2 * q]     = bba[2 * q]     + bflo(ba[q]);
                    zba[2 * q + 1] = bba[2 * q + 1] + bfhi(ba[q]);
                    zbb[2 * q]     = bbb[2 * q]     + bflo(bbv[q]);
                    zbb[2 * q + 1] = bbb[2 * q + 1] + bfhi(bbv[q]);
                }
            }
            float c1d[4], c2d[4];
#pragma unroll
            for (int t = 0; t < 4; ++t)
                c1d[t] = cb1t[t] + b2f(tabs[3 * nb + drow + t * 16 + l15]);
            if constexpr (LAYER >= 2) {
#pragma unroll
                for (int t = 0; t < 4; ++t)
                    c2d[t] = cb2t[t] + b2f(tabs[5 * nb + drow + t * 16 + l15]);
            }

            float nmT[4] = {0.f, 0.f, 0.f, 0.f}, dnT[4] = {0.f, 0.f, 0.f, 0.f};

            while (iC == i) {
                if (iN < ndst) ldrows(sedN, rowsN);
                int iF = iN, bF = bN;
                succ(iF, bF);
                int4 sedF = sedN;
                if (iF < ndst) sedF = ldsed(iF, bF);

                int cnt = min(endof(i) - bC, 16);
                float ex = __int_as_float(sedC.y), ey = __int_as_float(sedC.z);
                float za[8], zc[8];
#pragma unroll
                for (int q = 0; q < 4; ++q) {
                    za[2*q]   = fmaf(ex, w0a[2*q],   fmaf(ey, w1a[2*q],   zba[2*q]))   + bflo(rowsC.ra[q]);
                    za[2*q+1] = fmaf(ex, w0a[2*q+1], fmaf(ey, w1a[2*q+1], zba[2*q+1])) + bfhi(rowsC.ra[q]);
                    zc[2*q]   = fmaf(ex, w0b[2*q],   fmaf(ey, w1b[2*q],   zbb[2*q]))   + bflo(rowsC.rb[q]);
                    zc[2*q+1] = fmaf(ex, w0b[2*q+1], fmaf(ey, w1b[2*q+1], zbb[2*q+1])) + bfhi(rowsC.rb[q]);
                }
                *(iv4*)(Lhv + wlo) = rowsC.hva;  *(iv4*)(Lhv + whi) = rowsC.hvb;
                *(iv4*)(Lb1 + wlo) = rowsC.b1a;  *(iv4*)(Lb1 + whi) = rowsC.b1b;
                if constexpr (LAYER >= 2) {
                    *(iv4*)(Lb2 + wlo) = rowsC.b2a;  *(iv4*)(Lb2 + whi) = rowsC.b2b;
                }
                iv4 pa, pb;
#pragma unroll
                for (int q = 0; q < 4; ++q) {
                    pa[q] = pk2(fmaxf(za[2*q], 0.f), fmaxf(za[2*q+1], 0.f));
                    pb[q] = pk2(fmaxf(zc[2*q], 0.f), fmaxf(zc[2*q+1], 0.f));
                }
                short8 af0, af1;
                __builtin_memcpy(&af0, &pa, 16);
                __builtin_memcpy(&af1, &pb, 16);
                f32x4 acc[4];
#pragma unroll
                for (int t = 0; t < 4; ++t) {
                    f32x4 a;
#pragma unroll
                    for (int r = 0; r < 4; ++r) {
                        int row = lg * 4 + r;
                        int ad = (row * 128 + (t * 16 + l15) * 2) ^ ((row & 7) << 4);
                        a[r] = c1d[t] + b2f(*(const bf16*)(Lb1 + ad));
                    }
                    acc[t] = a;
                }
                __builtin_amdgcn_s_setprio(1);
#pragma unroll
                for (int t = 0; t < 4; ++t) {
                    short8 q0, q1;
                    __builtin_memcpy(&q0, cfr + ((t * 2 + 0) * 64 + lane) * 16, 16);
                    __builtin_memcpy(&q1, cfr + ((t * 2 + 1) * 64 + lane) * 16, 16);
                    acc[t] = __builtin_amdgcn_mfma_f32_16x16x32_bf16(af0, q0, acc[t], 0, 0, 0);
                    acc[t] = __builtin_amdgcn_mfma_f32_16x16x32_bf16(af1, q1, acc[t], 0, 0, 0);
                }
                __builtin_amdgcn_s_setprio(0);
                if constexpr (LAYER >= 2) {
#pragma unroll
                    for (int t = 0; t < 4; ++t)
#pragma unroll
                        for (int r = 0; r < 4; ++r) {
                            int row = lg * 4 + r;
                            int ad = (row * 128 + (t * 16 + l15) * 2) ^ ((row & 7) << 4);
                            *(unsigned short*)(Le1 + ad) =
                                __bfloat16_as_ushort(__float2bfloat16(fmaxf(acc[t][r], 0.f)));
                        }
                    short8 ag0, ag1;
                    __builtin_memcpy(&ag0, Le1 + ((l15 * 128 + kb * 2) ^ ((l15 & 7) << 4)), 16);
                    __builtin_memcpy(&ag1, Le1 + ((l15 * 128 + 64 + kb * 2) ^ ((l15 & 7) << 4)), 16);
#pragma unroll
                    for (int t = 0; t < 4; ++t) {
                        f32x4 a;
#pragma unroll
                        for (int r = 0; r < 4; ++r) {
                            int row = lg * 4 + r;
                            int ad = (row * 128 + (t * 16 + l15) * 2) ^ ((row & 7) << 4);
                            a[r] = c2d[t] + b2f(*(const bf16*)(Lb2 + ad));
                        }
                        acc[t] = a;
                    }
                    __builtin_amdgcn_s_setprio(1);
#pragma unroll
                    for (int t = 0; t < 4; ++t) {
                        short8 q0, q1;
                        __builtin_memcpy(&q0, cfr + 8192 + ((t * 2 + 0) * 64 + lane) * 16, 16);
                        __builtin_memcpy(&q1, cfr + 8192 + ((t * 2 + 1) * 64 + lane) * 16, 16);
                        acc[t] = __builtin_amdgcn_mfma_f32_16x16x32_bf16(ag0, q0, acc[t], 0, 0, 0);
                        acc[t] = __builtin_amdgcn_mfma_f32_16x16x32_bf16(ag1, q1, acc[t], 0, 0, 0);
                    }
                    __builtin_amdgcn_s_setprio(0);
                }
#pragma unroll
                for (int r = 0; r < 4; ++r) {
                    int row = lg * 4 + r;
                    bool valid = row < cnt;
#pragma unroll
                    for (int t = 0; t < 4; ++t) {
                        float sg = valid ? 1.f / (1.f + __expf(-acc[t][r])) : 0.f;
                        int ad = (row * 128 + (t * 16 + l15) * 2) ^ ((row & 7) << 4);
                        nmT[t] = fmaf(sg, b2f(*(const bf16*)(Lhv + ad)), nmT[t]);
                        dnT[t] += sg;
                    }
                }
                sedC = sedN; rowsC = rowsN; iC = iN; bC = bN;
                iN = iF; bN = bF; sedN = sedF;
            }

            float* fl = (float*)Le1;
#pragma unroll
            for (int m = 16; m < 64; m <<= 1)
#pragma unroll
                for (int t = 0; t < 4; ++t) {
                    nmT[t] += __shfl_xor(nmT[t], m);
                    dnT[t] += __shfl_xor(dnT[t], m);
                }
            if (lg == 0) {
#pragma unroll
                for (int t = 0; t < 4; ++t) {
                    fl[t * 16 + l15]      = nmT[t];
                    fl[64 + t * 16 + l15] = dnT[t];
                }
            }
            float nmv = fl[lane], dnv = fl[64 + lane];
            float hval = fmaxf(hu + nmv / (dnv + 1e-6f), 0.f);
            if constexpr (LAYER < 2) {
                h[drow + lane] = hval;
            } else {
                // fused prescore: ps[d] = h[d]@Wp[:64], pd[d] = h[d]@Wp[64:]
                float a = hval * wpa, b = hval * wpb;
#pragma unroll
                for (int m = 32; m; m >>= 1) {
                    a += __shfl_xor(a, m);
                    b += __shfl_xor(b, m);
                }
                if (lane == 0) { ps[dA + i] = a; pd[dA + i] = b; }
            }
        }
    }
}

// ---------------- scoring ----------------
__global__ void score2_k(const float* __restrict__ ps, const float* __restrict__ pd,
                         const float* __restrict__ bp, const int* __restrict__ ss,
                         const int* __restrict__ ds, float* __restrict__ out) {
    int i = blockIdx.x * blockDim.x + threadIdx.x;
    if (i < NS) out[i] = ps[ss[i]] + pd[ds[i]] + bp[0];
}

extern "C" void kernel_launch(void* const* d_in, const int* in_sizes, int n_in,
                              void* d_out, int out_size, void* d_ws, size_t ws_size,
                              hipStream_t stream) {
    const float* x  = (const float*)d_in[0];
    const float* e0 = (const float*)d_in[1];
    const float* Wn = (const float*)d_in[2];
    const float* bn = (const float*)d_in[3];
    const float* We = (const float*)d_in[4];
    const float* be = (const float*)d_in[5];
    const float* A  = (const float*)d_in[6];
    const float* B  = (const float*)d_in[7];
    const float* C  = (const float*)d_in[8];
    const float* cb = (const float*)d_in[9];
    const float* U  = (const float*)d_in[10];
    const float* V  = (const float*)d_in[11];
    const float* Wp = (const float*)d_in[12];
    const float* bp = (const float*)d_in[13];
    const int* src  = (const int*)d_in[14];
    const int* dst  = (const int*)d_in[15];
    const int* ss   = (const int*)d_in[16];
    const int* ds   = (const int*)d_in[17];

    char* ws = (char*)d_ws;
    size_t nb = (size_t)NN * HH;
    float* h      = (float*)ws;                    // 25.6 MB
    bf16*  tabs   = (bf16*)(ws + nb * 4);          // 8 x 12.8 MB  [A0,B0,A1,B1,A2,B2,hV,hU]
    int4*  sedge  = (int4*)(tabs + 8 * nb);        // 25.6 MB
    int*   cnt    = (int*)(sedge + NE);
    int*   rowptr = cnt + NN;
    int*   cursor = rowptr + (NN + 1);
    int*   bsum   = cursor + NN;
    int*   bofs   = bsum + SCAN_G;
    float* We0    = (float*)(bofs + SCAN_G);
    float* bb0    = We0 + 2 * HH;
    float* ps     = bb0 + HH;
    float* pd     = ps + NN;
    int*   wq     = (int*)(pd + NN);               // 4 queue counters

    prep_k<<<1, 64, 0, stream>>>(We, be, C, cb, We0, bb0);

    zero_int_k<<<(NN + 255) / 256, 256, 0, stream>>>(cnt, NN);
    zero_int_k<<<1, 64, 0, stream>>>(wq, 4);
    hist_k<<<(NE + 255) / 256, 256, 0, stream>>>(dst, cnt);
    scan1_k<<<SCAN_G, SCAN_B, 0, stream>>>(cnt, rowptr, bsum);
    scan2_k<<<1, 64, 0, stream>>>(bsum, bofs);
    scan3_k<<<SCAN_G, SCAN_B, 0, stream>>>(rowptr, cursor, bofs);
    scatter_k<<<(NE + 255) / 256, 256, 0, stream>>>(dst, src, (const float2*)e0,
                                                    cursor, sedge);

    for (int l = 0; l < 3; ++l) {
        if (l == 0)
            transform_mfma_k<true><<<dim3(128, 2), 256, 0, stream>>>(
                h, x, Wn, bn,
                A + (size_t)l * HH * HH, B + (size_t)l * HH * HH,
                V + (size_t)l * HH * HH, U + (size_t)l * HH * HH,
                tabs + 2 * (size_t)l * nb, tabs + (2 * (size_t)l + 1) * nb,
                tabs + 6 * nb, tabs + 7 * nb);
        else
            transform_mfma_k<false><<<dim3(128, 2), 256, 0, stream>>>(
                h, x, Wn, bn,
                A + (size_t)l * HH * HH, B + (size_t)l * HH * HH,
                V + (size_t)l * HH * HH, U + (size_t)l * HH * HH,
                tabs + 2 * (size_t)l * nb, tabs + (2 * (size_t)l + 1) * nb,
                tabs + 6 * nb, tabs + 7 * nb);
        if (l == 0)
            agg0_k<<<1024, 256, 0, stream>>>(h, tabs, We0, bb0, rowptr, sedge, wq + 0);
        else if (l == 1)
            agg_k<1><<<1024, 256, 0, stream>>>(h, tabs, We0, bb0, cb, C, rowptr, sedge,
                                               wq + 1, Wp, ps, pd);
        else
            agg_k<2><<<1024, 256, 0, stream>>>(h, tabs, We0, bb0, cb, C, rowptr, sedge,
                                               wq + 2, Wp, ps, pd);
    }

    score2_k<<<(NS + 255) / 256, 256, 0, stream>>>(ps, pd, bp, ss, ds, (float*)d_out);
}

// Round 14
// 923.001 us; speedup vs baseline: 1.4935x; 1.4935x over previous
//
#include <hip/hip_runtime.h>
#include <hip/hip_bf16.h>

using bf16 = __hip_bfloat16;
typedef __attribute__((ext_vector_type(8))) short short8;  // 8 bf16 (4 VGPRs)
typedef __attribute__((ext_vector_type(4))) float f32x4;   // MFMA C/D
typedef __attribute__((ext_vector_type(4))) int   iv4;     // 16B of packed bf16

static constexpr int NN = 100000;   // nodes
static constexpr int NE = 1600000;  // message edges
static constexpr int NS = 500000;   // scored edges
static constexpr int HH = 64;       // hidden
static constexpr int SCAN_B = 1024;
static constexpr int SCAN_G = (NN + SCAN_B - 1) / SCAN_B;   // 98
static constexpr int DPW = 8;       // dsts per wave (static grid-stride; r13's queue+DPW4 regressed)
static constexpr int NGRP = (NN + DPW - 1) / DPW;           // 12500

__device__ __forceinline__ float b2f(bf16 v) { return __bfloat162float(v); }
__device__ __forceinline__ float bflo(int u)  { return __uint_as_float(((unsigned)u) << 16); }
__device__ __forceinline__ float bfhi(int u)  { return __uint_as_float(((unsigned)u) & 0xffff0000u); }
__device__ __forceinline__ int pk2(float a, float b) {
    unsigned lo = __bfloat16_as_ushort(__float2bfloat16(a));
    unsigned hi = __bfloat16_as_ushort(__float2bfloat16(b));
    return (int)(lo | (hi << 16));
}
__device__ __forceinline__ int bcasti(int v, int k) {
    return __builtin_amdgcn_readlane(v, k);
}

// ---------------- weight prep ----------------

__global__ void prep_k(const float* __restrict__ We, const float* __restrict__ be,
                       const float* __restrict__ C0, const float* __restrict__ cb0,
                       float* __restrict__ We0, float* __restrict__ bb0) {
    int j = threadIdx.x;
    if (j >= HH) return;
    float s0 = 0.f, s1 = 0.f, sb = 0.f;
    for (int k = 0; k < HH; ++k) {
        float c = C0[k * HH + j];
        s0 = fmaf(We[k], c, s0);
        s1 = fmaf(We[HH + k], c, s1);
        sb = fmaf(be[k], c, sb);
    }
    We0[j] = s0; We0[HH + j] = s1; bb0[j] = sb + cb0[j];
}

// ---------------- CSR build ----------------

__global__ void zero_int_k(int* __restrict__ p, int n) {
    int i = blockIdx.x * blockDim.x + threadIdx.x;
    if (i < n) p[i] = 0;
}

__global__ void hist_k(const int* __restrict__ dst, int* __restrict__ cnt) {
    int i = blockIdx.x * blockDim.x + threadIdx.x;
    if (i < NE) atomicAdd(&cnt[dst[i]], 1);
}

__global__ void scan1_k(const int* __restrict__ cnt, int* __restrict__ rowptr,
                        int* __restrict__ bsum) {
    __shared__ int sm[SCAN_B];
    int t = threadIdx.x, idx = blockIdx.x * SCAN_B + t;
    int v = (idx < NN) ? cnt[idx] : 0;
    sm[t] = v;
    __syncthreads();
    for (int off = 1; off < SCAN_B; off <<= 1) {
        int add = (t >= off) ? sm[t - off] : 0;
        __syncthreads();
        sm[t] += add;
        __syncthreads();
    }
    if (idx < NN) rowptr[idx] = sm[t] - v;
    if (t == SCAN_B - 1) bsum[blockIdx.x] = sm[t];
}

__global__ void scan2_k(const int* __restrict__ bsum, int* __restrict__ bofs) {
    if (threadIdx.x == 0) {
        int acc = 0;
        for (int b = 0; b < SCAN_G; ++b) { bofs[b] = acc; acc += bsum[b]; }
    }
}

__global__ void scan3_k(int* __restrict__ rowptr, int* __restrict__ cursor,
                        const int* __restrict__ bofs) {
    int idx = blockIdx.x * SCAN_B + threadIdx.x;
    if (idx < NN) {
        int r = rowptr[idx] + bofs[blockIdx.x];
        rowptr[idx] = r;
        cursor[idx] = r;
    }
    if (idx == 0) rowptr[NN] = NE;
}

__global__ void scatter_k(const int* __restrict__ dst, const int* __restrict__ src,
                          const float2* __restrict__ e0, int* __restrict__ cursor,
                          int4* __restrict__ sedge) {
    int i = blockIdx.x * blockDim.x + threadIdx.x;
    if (i < NE) {
        int p = atomicAdd(&cursor[dst[i]], 1);
        float2 ev = e0[i];
        sedge[p] = make_int4(src[i], __float_as_int(ev.x), __float_as_int(ev.y), 0);
    }
}

// ---------------- MFMA node transforms: out = h @ W for (A,B) / (V,U) ----------------
// FIRST: h row computed on the fly from x@Wn+bn (layer 0 — no encode kernel).
template <bool FIRST>
__global__ __launch_bounds__(256, 2)
void transform_mfma_k(const float* __restrict__ h, const float* __restrict__ x,
                      const float* __restrict__ Wn, const float* __restrict__ bn,
                      const float* __restrict__ A, const float* __restrict__ B,
                      const float* __restrict__ V, const float* __restrict__ U,
                      bf16* __restrict__ oA, bf16* __restrict__ oB,
                      bf16* __restrict__ oV, bf16* __restrict__ oU) {
    __shared__ __align__(16) char lds_all[4 * 2048];
    char* lds = lds_all + (threadIdx.x >> 6) * 2048;
    const int lane = threadIdx.x & 63;
    const int l15 = lane & 15, lg = lane >> 4, kb = lg * 8;
    const float *W0, *W1; bf16 *o0, *o1;
    if (blockIdx.y == 0) { W0 = A; W1 = B; o0 = oA; o1 = oB; }
    else                 { W0 = V; W1 = U; o0 = oV; o1 = oU; }

    short8 wf[2][4][2];
#pragma unroll
    for (int m = 0; m < 2; ++m) {
        const float* W = m ? W1 : W0;
#pragma unroll
        for (int t = 0; t < 4; ++t)
#pragma unroll
            for (int f = 0; f < 2; ++f) {
                iv4 q;
#pragma unroll
                for (int j = 0; j < 4; ++j)
                    q[j] = pk2(W[(f * 32 + kb + 2 * j) * HH + t * 16 + l15],
                               W[(f * 32 + kb + 2 * j + 1) * HH + t * 16 + l15]);
                __builtin_memcpy(&wf[m][t][f], &q, 16);
            }
    }
    const int sw = (l15 & 7) << 4;
    int wave = blockIdx.x * 4 + (threadIdx.x >> 6);
    int nw = gridDim.x * 4;
    for (int tile = wave; tile < NN / 16; tile += nw) {
        int row0 = tile * 16;
        iv4 pa, pb;
        if constexpr (FIRST) {
            float2 xv = *(const float2*)(x + 2 * (size_t)(row0 + l15));
#pragma unroll
            for (int j = 0; j < 4; ++j) {
                int k0 = kb + 2 * j;
                pa[j] = pk2(fmaf(xv.x, Wn[k0],     fmaf(xv.y, Wn[HH + k0],     bn[k0])),
                            fmaf(xv.x, Wn[k0 + 1], fmaf(xv.y, Wn[HH + k0 + 1], bn[k0 + 1])));
                int k1 = 32 + kb + 2 * j;
                pb[j] = pk2(fmaf(xv.x, Wn[k1],     fmaf(xv.y, Wn[HH + k1],     bn[k1])),
                            fmaf(xv.x, Wn[k1 + 1], fmaf(xv.y, Wn[HH + k1 + 1], bn[k1 + 1])));
            }
        } else {
            const float* hr = h + (size_t)(row0 + l15) * HH + kb;
            float4 v0 = *(const float4*)(hr);
            float4 v1 = *(const float4*)(hr + 4);
            float4 v2 = *(const float4*)(hr + 32);
            float4 v3 = *(const float4*)(hr + 36);
            pa[0] = pk2(v0.x, v0.y); pa[1] = pk2(v0.z, v0.w);
            pa[2] = pk2(v1.x, v1.y); pa[3] = pk2(v1.z, v1.w);
            pb[0] = pk2(v2.x, v2.y); pb[1] = pk2(v2.z, v2.w);
            pb[2] = pk2(v3.x, v3.y); pb[3] = pk2(v3.z, v3.w);
        }
        short8 af0, af1;
        __builtin_memcpy(&af0, &pa, 16);
        __builtin_memcpy(&af1, &pb, 16);
#pragma unroll
        for (int m = 0; m < 2; ++m) {
            f32x4 acc[4];
#pragma unroll
            for (int t = 0; t < 4; ++t) acc[t] = f32x4{0.f, 0.f, 0.f, 0.f};
#pragma unroll
            for (int t = 0; t < 4; ++t) {
                acc[t] = __builtin_amdgcn_mfma_f32_16x16x32_bf16(af0, wf[m][t][0], acc[t], 0, 0, 0);
                acc[t] = __builtin_amdgcn_mfma_f32_16x16x32_bf16(af1, wf[m][t][1], acc[t], 0, 0, 0);
            }
#pragma unroll
            for (int t = 0; t < 4; ++t)
#pragma unroll
                for (int r = 0; r < 4; ++r) {
                    int row = lg * 4 + r;
                    int ad = (row * 128 + (t * 16 + l15) * 2) ^ ((row & 7) << 4);
                    *(unsigned short*)(lds + ad) =
                        __bfloat16_as_ushort(__float2bfloat16(acc[t][r]));
                }
            int base = l15 * 128 + lg * 32;
            iv4 q0, q1;
            __builtin_memcpy(&q0, lds + ((base) ^ sw), 16);
            __builtin_memcpy(&q1, lds + ((base + 16) ^ sw), 16);
            bf16* out = m ? o1 : o0;
            *(iv4*)(out + (size_t)(row0 + l15) * HH + lg * 16) = q0;
            *(iv4*)(out + (size_t)(row0 + l15) * HH + lg * 16 + 8) = q1;
        }
    }
}

// ---------------- layer-0 aggregate: lane = 4 feats x 4 edge-slots ----------------
__global__ __launch_bounds__(256, 2)
void agg0_k(float* __restrict__ h, const bf16* __restrict__ tabs,
            const float* __restrict__ We0, const float* __restrict__ bb0,
            const int* __restrict__ rowptr, const int4* __restrict__ sedge) {
    __shared__ float fl_all[4][128];
    float* fl = fl_all[threadIdx.x >> 6];
    const int lane = threadIdx.x & 63;
    const int l15 = lane & 15, lg = lane >> 4;
    const int f0 = l15 * 4;
    const size_t nb = (size_t)NN * HH;

    float w0f[4], w1f[4], bbf[4];
#pragma unroll
    for (int q = 0; q < 4; ++q) {
        w0f[q] = We0[f0 + q];
        w1f[q] = We0[HH + f0 + q];
        bbf[q] = bb0[f0 + q];
    }

    struct R0 { uint2 a0[4], hv[4]; };
    const int nwaves = gridDim.x * 4;
    for (int g = blockIdx.x * 4 + (threadIdx.x >> 6); g < NGRP; g += nwaves) {
        int dA = g * DPW;
        int ndst = min(DPW, NN - dA);
        int rpv = rowptr[dA + min(lane, ndst)];

        auto endof = [&](int i2) { return bcasti(rpv, i2 + 1); };
        auto begof = [&](int i2) { return bcasti(rpv, i2); };
        auto ldsed = [&](int i2, int b2) -> int4 {
            int en = endof(i2);
            int idx = b2 + min(l15, en - b2 - 1);
            return sedge[idx];
        };
        auto ldrows = [&](const int4& sd, R0& R) {
#pragma unroll
            for (int r = 0; r < 4; ++r) {
                int s = __shfl(sd.x, lg + 4 * r);
                R.a0[r] = *(const uint2*)(tabs + (size_t)s * HH + f0);
                R.hv[r] = *(const uint2*)(tabs + 6 * nb + (size_t)s * HH + f0);
            }
        };
        auto succ = [&](int& i2, int& b2) {
            if (i2 >= ndst) return;
            if (b2 + 16 < endof(i2)) { b2 += 16; return; }
            i2++;
            while (i2 < ndst && endof(i2) <= begof(i2)) i2++;
            if (i2 < ndst) b2 = begof(i2);
        };

        int iC = 0;
        while (iC < ndst && endof(iC) <= begof(iC)) iC++;
        int bC = (iC < ndst) ? begof(iC) : 0;
        int4 sedC = make_int4(0, 0, 0, 0), sedN = sedC;
        R0 rowsC, rowsN;
        if (iC < ndst) sedC = ldsed(iC, bC);
        int iN = iC, bN = bC;
        if (iC < ndst) succ(iN, bN);
        if (iN < ndst) sedN = ldsed(iN, bN);
        if (iC < ndst) ldrows(sedC, rowsC);

        for (int i = 0; i < ndst; ++i) {
            size_t drow = (size_t)(dA + i) * HH;
            float hu = b2f(tabs[7 * nb + drow + lane]);
            float zb[4];
            {
                uint2 bv = *(const uint2*)(tabs + nb + drow + f0);
                zb[0] = bbf[0] + bflo(bv.x); zb[1] = bbf[1] + bfhi(bv.x);
                zb[2] = bbf[2] + bflo(bv.y); zb[3] = bbf[3] + bfhi(bv.y);
            }
            float nm[4] = {0.f, 0.f, 0.f, 0.f}, dn[4] = {0.f, 0.f, 0.f, 0.f};

            while (iC == i) {
                if (iN < ndst) ldrows(sedN, rowsN);
                int iF = iN, bF = bN;
                succ(iF, bF);
                int4 sedF = sedN;
                if (iF < ndst) sedF = ldsed(iF, bF);

                int cnt = min(endof(i) - bC, 16);
#pragma unroll
                for (int r = 0; r < 4; ++r) {
                    int s = lg + 4 * r;
                    bool valid = s < cnt;
                    float ex = __int_as_float(__shfl(sedC.y, s));
                    float ey = __int_as_float(__shfl(sedC.z, s));
                    uint2 a0 = rowsC.a0[r], hv = rowsC.hv[r];
                    float av[4] = {bflo(a0.x), bfhi(a0.x), bflo(a0.y), bfhi(a0.y)};
                    float hvv[4] = {bflo(hv.x), bfhi(hv.x), bflo(hv.y), bfhi(hv.y)};
#pragma unroll
                    for (int q = 0; q < 4; ++q) {
                        float z = fmaf(ex, w0f[q], fmaf(ey, w1f[q], zb[q])) + av[q];
                        float sg = valid ? 1.f / (1.f + __expf(-z)) : 0.f;
                        nm[q] = fmaf(sg, hvv[q], nm[q]);
                        dn[q] += sg;
                    }
                }
                sedC = sedN; rowsC = rowsN; iC = iN; bC = bN;
                iN = iF; bN = bF; sedN = sedF;
            }

#pragma unroll
            for (int m = 16; m < 64; m <<= 1)
#pragma unroll
                for (int q = 0; q < 4; ++q) {
                    nm[q] += __shfl_xor(nm[q], m);
                    dn[q] += __shfl_xor(dn[q], m);
                }
            if (lg == 0) {
#pragma unroll
                for (int q = 0; q < 4; ++q) {
                    fl[f0 + q] = nm[q];
                    fl[64 + f0 + q] = dn[q];
                }
            }
            float nmv = fl[lane], dnv = fl[64 + lane];
            h[drow + lane] = fmaxf(hu + nmv / (dnv + 1e-6f), 0.f);
        }
    }
}

// ---------------- layers 1/2 aggregate (static grid-stride; prescore fused in L2) ----
struct Rows { iv4 ra, rb, hva, hvb, b1a, b1b, b2a, b2b; };

template <int LAYER>
__global__ __launch_bounds__(256, 2)
void agg_k(float* __restrict__ h, const bf16* __restrict__ tabs,
           const float* __restrict__ We0, const float* __restrict__ bb0,
           const float* __restrict__ cb, const float* __restrict__ C,
           const int* __restrict__ rowptr, const int4* __restrict__ sedge,
           const float* __restrict__ Wp, float* __restrict__ ps, float* __restrict__ pd) {
    __shared__ __align__(16) char cfr[LAYER >= 2 ? 16384 : 8192];
    constexpr int WLDS = (LAYER == 1 ? 4096 : 6144);
    __shared__ __align__(16) char lds_all[4 * WLDS];
    char* lds = lds_all + (threadIdx.x >> 6) * WLDS;
    char* Lb1 = lds;
    char* Lb2 = lds + 2048;
    char* Lhv = lds + (LAYER >= 2 ? 4096 : 2048);
    char* Le1 = lds;
    const int lane = threadIdx.x & 63;
    const int l15 = lane & 15, lg = lane >> 4, kb = lg * 8;
    const size_t nb = (size_t)NN * HH;

    {
        int t = threadIdx.x >> 6;
        const float* C1 = C + 1 * HH * HH;
        const float* C2 = C + 2 * HH * HH;
#pragma unroll
        for (int f = 0; f < 2; ++f) {
            iv4 q;
#pragma unroll
            for (int j = 0; j < 4; ++j)
                q[j] = pk2(C1[(f * 32 + kb + 2 * j) * HH + t * 16 + l15],
                           C1[(f * 32 + kb + 2 * j + 1) * HH + t * 16 + l15]);
            *(iv4*)(cfr + ((t * 2 + f) * 64 + lane) * 16) = q;
            if constexpr (LAYER >= 2) {
                iv4 p;
#pragma unroll
                for (int j = 0; j < 4; ++j)
                    p[j] = pk2(C2[(f * 32 + kb + 2 * j) * HH + t * 16 + l15],
                               C2[(f * 32 + kb + 2 * j + 1) * HH + t * 16 + l15]);
                *(iv4*)(cfr + 8192 + ((t * 2 + f) * 64 + lane) * 16) = p;
            }
        }
        __syncthreads();
    }

    float w0a[8], w0b[8], w1a[8], w1b[8], bba[8], bbb[8];
#pragma unroll
    for (int j = 0; j < 8; ++j) {
        w0a[j] = We0[kb + j];        w0b[j] = We0[32 + kb + j];
        w1a[j] = We0[HH + kb + j];   w1b[j] = We0[HH + 32 + kb + j];
        bba[j] = bb0[kb + j];        bbb[j] = bb0[32 + kb + j];
    }
    float cb1t[4], cb2t[4];
#pragma unroll
    for (int t = 0; t < 4; ++t) cb1t[t] = cb[HH + t * 16 + l15];
    if constexpr (LAYER >= 2) {
#pragma unroll
        for (int t = 0; t < 4; ++t) cb2t[t] = cb[2 * HH + t * 16 + l15];
    }
    float wpa = 0.f, wpb = 0.f;
    if constexpr (LAYER >= 2) { wpa = Wp[lane]; wpb = Wp[HH + lane]; }
    const int wlo = (l15 * 128 + lg * 16) ^ ((l15 & 7) << 4);
    const int whi = (l15 * 128 + 64 + lg * 16) ^ ((l15 & 7) << 4);

    const int nwaves = gridDim.x * 4;
    for (int g = blockIdx.x * 4 + (threadIdx.x >> 6); g < NGRP; g += nwaves) {
        int dA = g * DPW;
        int ndst = min(DPW, NN - dA);
        int rpv = rowptr[dA + min(lane, ndst)];

        auto endof = [&](int i2) { return bcasti(rpv, i2 + 1); };
        auto begof = [&](int i2) { return bcasti(rpv, i2); };
        auto ldsed = [&](int i2, int b2) -> int4 {
            int en = endof(i2);
            int idx = b2 + min(l15, en - b2 - 1);
            return sedge[idx];
        };
        auto ldrows = [&](const int4& sd, Rows& R) {
            size_t srow = (size_t)sd.x * HH;
            R.ra  = *(const iv4*)(tabs + srow + kb);
            R.rb  = *(const iv4*)(tabs + srow + 32 + kb);
            R.hva = *(const iv4*)(tabs + 6 * nb + srow + kb);
            R.hvb = *(const iv4*)(tabs + 6 * nb + srow + 32 + kb);
            R.b1a = *(const iv4*)(tabs + 2 * nb + srow + kb);
            R.b1b = *(const iv4*)(tabs + 2 * nb + srow + 32 + kb);
            if constexpr (LAYER >= 2) {
                R.b2a = *(const iv4*)(tabs + 4 * nb + srow + kb);
                R.b2b = *(const iv4*)(tabs + 4 * nb + srow + 32 + kb);
            }
        };
        auto succ = [&](int& i2, int& b2) {
            if (i2 >= ndst) return;
            if (b2 + 16 < endof(i2)) { b2 += 16; return; }
            i2++;
            while (i2 < ndst && endof(i2) <= begof(i2)) i2++;
            if (i2 < ndst) b2 = begof(i2);
        };

        int iC = 0;
        while (iC < ndst && endof(iC) <= begof(iC)) iC++;
        int bC = (iC < ndst) ? begof(iC) : 0;
        int4 sedC = make_int4(0, 0, 0, 0), sedN = sedC;
        Rows rowsC, rowsN;
        if (iC < ndst) sedC = ldsed(iC, bC);
        int iN = iC, bN = bC;
        if (iC < ndst) succ(iN, bN);
        if (iN < ndst) sedN = ldsed(iN, bN);
        if (iC < ndst) ldrows(sedC, rowsC);

        for (int i = 0; i < ndst; ++i) {
            size_t drow = (size_t)(dA + i) * HH;
            float hu = b2f(tabs[7 * nb + drow + lane]);
            float zba[8], zbb[8];
            {
                iv4 ba  = *(const iv4*)(tabs + nb + drow + kb);
                iv4 bbv = *(const iv4*)(tabs + nb + drow + 32 + kb);
#pragma unroll
                for (int q = 0; q < 4; ++q) {
                    zba[2 * q]     = bba[2 * q]     + bflo(ba[q]);
                    zba[2 * q + 1] = bba[2 * q + 1] + bfhi(ba[q]);
                    zbb[2 * q]     = bbb[2 * q]     + bflo(bbv[q]);
                    zbb[2 * q + 1] = bbb[2 * q + 1] + bfhi(bbv[q]);
                }
            }
            float c1d[4], c2d[4];
#pragma unroll
            for (int t = 0; t < 4; ++t)
                c1d[t] = cb1t[t] + b2f(tabs[3 * nb + drow + t * 16 + l15]);
            if constexpr (LAYER >= 2) {
#pragma unroll
                for (int t = 0; t < 4; ++t)
                    c2d[t] = cb2t[t] + b2f(tabs[5 * nb + drow + t * 16 + l15]);
            }

            float nmT[4] = {0.f, 0.f, 0.f, 0.f}, dnT[4] = {0.f, 0.f, 0.f, 0.f};

            while (iC == i) {
                if (iN < ndst) ldrows(sedN, rowsN);
                int iF = iN, bF = bN;
                succ(iF, bF);
                int4 sedF = sedN;
                if (iF < ndst) sedF = ldsed(iF, bF);

                int cnt = min(endof(i) - bC, 16);
                float ex = __int_as_float(sedC.y), ey = __int_as_float(sedC.z);
                float za[8], zc[8];
#pragma unroll
                for (int q = 0; q < 4; ++q) {
                    za[2*q]   = fmaf(ex, w0a[2*q],   fmaf(ey, w1a[2*q],   zba[2*q]))   + bflo(rowsC.ra[q]);
                    za[2*q+1] = fmaf(ex, w0a[2*q+1], fmaf(ey, w1a[2*q+1], zba[2*q+1])) + bfhi(rowsC.ra[q]);
                    zc[2*q]   = fmaf(ex, w0b[2*q],   fmaf(ey, w1b[2*q],   zbb[2*q]))   + bflo(rowsC.rb[q]);
                    zc[2*q+1] = fmaf(ex, w0b[2*q+1], fmaf(ey, w1b[2*q+1], zbb[2*q+1])) + bfhi(rowsC.rb[q]);
                }
                *(iv4*)(Lhv + wlo) = rowsC.hva;  *(iv4*)(Lhv + whi) = rowsC.hvb;
                *(iv4*)(Lb1 + wlo) = rowsC.b1a;  *(iv4*)(Lb1 + whi) = rowsC.b1b;
                if constexpr (LAYER >= 2) {
                    *(iv4*)(Lb2 + wlo) = rowsC.b2a;  *(iv4*)(Lb2 + whi) = rowsC.b2b;
                }
                iv4 pa, pb;
#pragma unroll
                for (int q = 0; q < 4; ++q) {
                    pa[q] = pk2(fmaxf(za[2*q], 0.f), fmaxf(za[2*q+1], 0.f));
                    pb[q] = pk2(fmaxf(zc[2*q], 0.f), fmaxf(zc[2*q+1], 0.f));
                }
                short8 af0, af1;
                __builtin_memcpy(&af0, &pa, 16);
                __builtin_memcpy(&af1, &pb, 16);
                f32x4 acc[4];
#pragma unroll
                for (int t = 0; t < 4; ++t) {
                    f32x4 a;
#pragma unroll
                    for (int r = 0; r < 4; ++r) {
                        int row = lg * 4 + r;
                        int ad = (row * 128 + (t * 16 + l15) * 2) ^ ((row & 7) << 4);
                        a[r] = c1d[t] + b2f(*(const bf16*)(Lb1 + ad));
                    }
                    acc[t] = a;
                }
                __builtin_amdgcn_s_setprio(1);
#pragma unroll
                for (int t = 0; t < 4; ++t) {
                    short8 q0, q1;
                    __builtin_memcpy(&q0, cfr + ((t * 2 + 0) * 64 + lane) * 16, 16);
                    __builtin_memcpy(&q1, cfr + ((t * 2 + 1) * 64 + lane) * 16, 16);
                    acc[t] = __builtin_amdgcn_mfma_f32_16x16x32_bf16(af0, q0, acc[t], 0, 0, 0);
                    acc[t] = __builtin_amdgcn_mfma_f32_16x16x32_bf16(af1, q1, acc[t], 0, 0, 0);
                }
                __builtin_amdgcn_s_setprio(0);
                if constexpr (LAYER >= 2) {
#pragma unroll
                    for (int t = 0; t < 4; ++t)
#pragma unroll
                        for (int r = 0; r < 4; ++r) {
                            int row = lg * 4 + r;
                            int ad = (row * 128 + (t * 16 + l15) * 2) ^ ((row & 7) << 4);
                            *(unsigned short*)(Le1 + ad) =
                                __bfloat16_as_ushort(__float2bfloat16(fmaxf(acc[t][r], 0.f)));
                        }
                    short8 ag0, ag1;
                    __builtin_memcpy(&ag0, Le1 + ((l15 * 128 + kb * 2) ^ ((l15 & 7) << 4)), 16);
                    __builtin_memcpy(&ag1, Le1 + ((l15 * 128 + 64 + kb * 2) ^ ((l15 & 7) << 4)), 16);
#pragma unroll
                    for (int t = 0; t < 4; ++t) {
                        f32x4 a;
#pragma unroll
                        for (int r = 0; r < 4; ++r) {
                            int row = lg * 4 + r;
                            int ad = (row * 128 + (t * 16 + l15) * 2) ^ ((row & 7) << 4);
                            a[r] = c2d[t] + b2f(*(const bf16*)(Lb2 + ad));
                        }
                        acc[t] = a;
                    }
                    __builtin_amdgcn_s_setprio(1);
#pragma unroll
                    for (int t = 0; t < 4; ++t) {
                        short8 q0, q1;
                        __builtin_memcpy(&q0, cfr + 8192 + ((t * 2 + 0) * 64 + lane) * 16, 16);
                        __builtin_memcpy(&q1, cfr + 8192 + ((t * 2 + 1) * 64 + lane) * 16, 16);
                        acc[t] = __builtin_amdgcn_mfma_f32_16x16x32_bf16(ag0, q0, acc[t], 0, 0, 0);
                        acc[t] = __builtin_amdgcn_mfma_f32_16x16x32_bf16(ag1, q1, acc[t], 0, 0, 0);
                    }
                    __builtin_amdgcn_s_setprio(0);
                }
#pragma unroll
                for (int r = 0; r < 4; ++r) {
                    int row = lg * 4 + r;
                    bool valid = row < cnt;
#pragma unroll
                    for (int t = 0; t < 4; ++t) {
                        float sg = valid ? 1.f / (1.f + __expf(-acc[t][r])) : 0.f;
                        int ad = (row * 128 + (t * 16 + l15) * 2) ^ ((row & 7) << 4);
                        nmT[t] = fmaf(sg, b2f(*(const bf16*)(Lhv + ad)), nmT[t]);
                        dnT[t] += sg;
                    }
                }
                sedC = sedN; rowsC = rowsN; iC = iN; bC = bN;
                iN = iF; bN = bF; sedN = sedF;
            }

            float* fl = (float*)Le1;
#pragma unroll
            for (int m = 16; m < 64; m <<= 1)
#pragma unroll
                for (int t = 0; t < 4; ++t) {
                    nmT[t] += __shfl_xor(nmT[t], m);
                    dnT[t] += __shfl_xor(dnT[t], m);
                }
            if (lg == 0) {
#pragma unroll
                for (int t = 0; t < 4; ++t) {
                    fl[t * 16 + l15]      = nmT[t];
                    fl[64 + t * 16 + l15] = dnT[t];
                }
            }
            float nmv = fl[lane], dnv = fl[64 + lane];
            float hval = fmaxf(hu + nmv / (dnv + 1e-6f), 0.f);
            if constexpr (LAYER < 2) {
                h[drow + lane] = hval;
            } else {
                // fused prescore: ps[d] = h[d]@Wp[:64], pd[d] = h[d]@Wp[64:]
                float a = hval * wpa, b = hval * wpb;
#pragma unroll
                for (int m = 32; m; m >>= 1) {
                    a += __shfl_xor(a, m);
                    b += __shfl_xor(b, m);
                }
                if (lane == 0) { ps[dA + i] = a; pd[dA + i] = b; }
            }
        }
    }
}

// ---------------- scoring ----------------
__global__ void score2_k(const float* __restrict__ ps, const float* __restrict__ pd,
                         const float* __restrict__ bp, const int* __restrict__ ss,
                         const int* __restrict__ ds, float* __restrict__ out) {
    int i = blockIdx.x * blockDim.x + threadIdx.x;
    if (i < NS) out[i] = ps[ss[i]] + pd[ds[i]] + bp[0];
}

extern "C" void kernel_launch(void* const* d_in, const int* in_sizes, int n_in,
                              void* d_out, int out_size, void* d_ws, size_t ws_size,
                              hipStream_t stream) {
    const float* x  = (const float*)d_in[0];
    const float* e0 = (const float*)d_in[1];
    const float* Wn = (const float*)d_in[2];
    const float* bn = (const float*)d_in[3];
    const float* We = (const float*)d_in[4];
    const float* be = (const float*)d_in[5];
    const float* A  = (const float*)d_in[6];
    const float* B  = (const float*)d_in[7];
    const float* C  = (const float*)d_in[8];
    const float* cb = (const float*)d_in[9];
    const float* U  = (const float*)d_in[10];
    const float* V  = (const float*)d_in[11];
    const float* Wp = (const float*)d_in[12];
    const float* bp = (const float*)d_in[13];
    const int* src  = (const int*)d_in[14];
    const int* dst  = (const int*)d_in[15];
    const int* ss   = (const int*)d_in[16];
    const int* ds   = (const int*)d_in[17];

    char* ws = (char*)d_ws;
    size_t nb = (size_t)NN * HH;
    float* h      = (float*)ws;                    // 25.6 MB
    bf16*  tabs   = (bf16*)(ws + nb * 4);          // 8 x 12.8 MB  [A0,B0,A1,B1,A2,B2,hV,hU]
    int4*  sedge  = (int4*)(tabs + 8 * nb);        // 25.6 MB
    int*   cnt    = (int*)(sedge + NE);
    int*   rowptr = cnt + NN;
    int*   cursor = rowptr + (NN + 1);
    int*   bsum   = cursor + NN;
    int*   bofs   = bsum + SCAN_G;
    float* We0    = (float*)(bofs + SCAN_G);
    float* bb0    = We0 + 2 * HH;
    float* ps     = bb0 + HH;
    float* pd     = ps + NN;

    prep_k<<<1, 64, 0, stream>>>(We, be, C, cb, We0, bb0);

    zero_int_k<<<(NN + 255) / 256, 256, 0, stream>>>(cnt, NN);
    hist_k<<<(NE + 255) / 256, 256, 0, stream>>>(dst, cnt);
    scan1_k<<<SCAN_G, SCAN_B, 0, stream>>>(cnt, rowptr, bsum);
    scan2_k<<<1, 64, 0, stream>>>(bsum, bofs);
    scan3_k<<<SCAN_G, SCAN_B, 0, stream>>>(rowptr, cursor, bofs);
    scatter_k<<<(NE + 255) / 256, 256, 0, stream>>>(dst, src, (const float2*)e0,
                                                    cursor, sedge);

    for (int l = 0; l < 3; ++l) {
        if (l == 0)
            transform_mfma_k<true><<<dim3(128, 2), 256, 0, stream>>>(
                h, x, Wn, bn,
                A + (size_t)l * HH * HH, B + (size_t)l * HH * HH,
                V + (size_t)l * HH * HH, U + (size_t)l * HH * HH,
                tabs + 2 * (size_t)l * nb, tabs + (2 * (size_t)l + 1) * nb,
                tabs + 6 * nb, tabs + 7 * nb);
        else
            transform_mfma_k<false><<<dim3(128, 2), 256, 0, stream>>>(
                h, x, Wn, bn,
                A + (size_t)l * HH * HH, B + (size_t)l * HH * HH,
                V + (size_t)l * HH * HH, U + (size_t)l * HH * HH,
                tabs + 2 * (size_t)l * nb, tabs + (2 * (size_t)l + 1) * nb,
                tabs + 6 * nb, tabs + 7 * nb);
        if (l == 0)
            agg0_k<<<1024, 256, 0, stream>>>(h, tabs, We0, bb0, rowptr, sedge);
        else if (l == 1)
            agg_k<1><<<1024, 256, 0, stream>>>(h, tabs, We0, bb0, cb, C, rowptr, sedge,
                                               Wp, ps, pd);
        else
            agg_k<2><<<1024, 256, 0, stream>>>(h, tabs, We0, bb0, cb, C, rowptr, sedge,
                                               Wp, ps, pd);
    }

    score2_k<<<(NS + 255) / 256, 256, 0, stream>>>(ps, pd, bp, ss, ds, (float*)d_out);
}

// Round 15
// 909.554 us; speedup vs baseline: 1.5156x; 1.0148x over previous
//
#include <hip/hip_runtime.h>
#include <hip/hip_bf16.h>

using bf16 = __hip_bfloat16;
typedef __attribute__((ext_vector_type(8))) short short8;  // 8 bf16 (4 VGPRs)
typedef __attribute__((ext_vector_type(4))) float f32x4;   // MFMA C/D
typedef __attribute__((ext_vector_type(4))) int   iv4;     // 16B of packed bf16

static constexpr int NN = 100000;   // nodes
static constexpr int NE = 1600000;  // message edges
static constexpr int NS = 500000;   // scored edges
static constexpr int HH = 64;       // hidden
static constexpr int SCAN_B = 1024;
static constexpr int SCAN_G = (NN + SCAN_B - 1) / SCAN_B;   // 98
static constexpr int DPW = 8;       // dsts per wave-group
static constexpr int NGRP = (NN + DPW - 1) / DPW;           // 12500
static constexpr int AGG_BLOCKS = 1024;
static constexpr int AGG_WAVES = AGG_BLOCKS * 4;            // 4096
static constexpr int NSTATIC = 3 * AGG_WAVES;               // 12288 static groups; 212 queued

__device__ __forceinline__ float b2f(bf16 v) { return __bfloat162float(v); }
__device__ __forceinline__ float bflo(int u)  { return __uint_as_float(((unsigned)u) << 16); }
__device__ __forceinline__ float bfhi(int u)  { return __uint_as_float(((unsigned)u) & 0xffff0000u); }
__device__ __forceinline__ int pk2(float a, float b) {
    unsigned lo = __bfloat16_as_ushort(__float2bfloat16(a));
    unsigned hi = __bfloat16_as_ushort(__float2bfloat16(b));
    return (int)(lo | (hi << 16));
}
__device__ __forceinline__ int bcasti(int v, int k) {
    return __builtin_amdgcn_readlane(v, k);
}

// ---------------- weight prep ----------------

__global__ void prep_k(const float* __restrict__ We, const float* __restrict__ be,
                       const float* __restrict__ C0, const float* __restrict__ cb0,
                       float* __restrict__ We0, float* __restrict__ bb0) {
    int j = threadIdx.x;
    if (j >= HH) return;
    float s0 = 0.f, s1 = 0.f, sb = 0.f;
    for (int k = 0; k < HH; ++k) {
        float c = C0[k * HH + j];
        s0 = fmaf(We[k], c, s0);
        s1 = fmaf(We[HH + k], c, s1);
        sb = fmaf(be[k], c, sb);
    }
    We0[j] = s0; We0[HH + j] = s1; bb0[j] = sb + cb0[j];
}

// ---------------- CSR build ----------------

__global__ void zero_int_k(int* __restrict__ p, int n) {
    int i = blockIdx.x * blockDim.x + threadIdx.x;
    if (i < n) p[i] = 0;
}

__global__ void hist_k(const int* __restrict__ dst, int* __restrict__ cnt) {
    int i = blockIdx.x * blockDim.x + threadIdx.x;
    if (i < NE) atomicAdd(&cnt[dst[i]], 1);
}

__global__ void scan1_k(const int* __restrict__ cnt, int* __restrict__ rowptr,
                        int* __restrict__ bsum) {
    __shared__ int sm[SCAN_B];
    int t = threadIdx.x, idx = blockIdx.x * SCAN_B + t;
    int v = (idx < NN) ? cnt[idx] : 0;
    sm[t] = v;
    __syncthreads();
    for (int off = 1; off < SCAN_B; off <<= 1) {
        int add = (t >= off) ? sm[t - off] : 0;
        __syncthreads();
        sm[t] += add;
        __syncthreads();
    }
    if (idx < NN) rowptr[idx] = sm[t] - v;
    if (t == SCAN_B - 1) bsum[blockIdx.x] = sm[t];
}

__global__ void scan2_k(const int* __restrict__ bsum, int* __restrict__ bofs) {
    if (threadIdx.x == 0) {
        int acc = 0;
        for (int b = 0; b < SCAN_G; ++b) { bofs[b] = acc; acc += bsum[b]; }
    }
}

__global__ void scan3_k(int* __restrict__ rowptr, int* __restrict__ cursor,
                        const int* __restrict__ bofs) {
    int idx = blockIdx.x * SCAN_B + threadIdx.x;
    if (idx < NN) {
        int r = rowptr[idx] + bofs[blockIdx.x];
        rowptr[idx] = r;
        cursor[idx] = r;
    }
    if (idx == 0) rowptr[NN] = NE;
}

__global__ void scatter_k(const int* __restrict__ dst, const int* __restrict__ src,
                          const float2* __restrict__ e0, int* __restrict__ cursor,
                          int4* __restrict__ sedge) {
    int i = blockIdx.x * blockDim.x + threadIdx.x;
    if (i < NE) {
        int p = atomicAdd(&cursor[dst[i]], 1);
        float2 ev = e0[i];
        sedge[p] = make_int4(src[i], __float_as_int(ev.x), __float_as_int(ev.y), 0);
    }
}

// ---------------- MFMA node transforms: out = h @ W for (A,B) / (V,U) ----------------
// FIRST: h row computed on the fly from x@Wn+bn (layer 0 — no encode kernel).
template <bool FIRST>
__global__ __launch_bounds__(256, 2)
void transform_mfma_k(const float* __restrict__ h, const float* __restrict__ x,
                      const float* __restrict__ Wn, const float* __restrict__ bn,
                      const float* __restrict__ A, const float* __restrict__ B,
                      const float* __restrict__ V, const float* __restrict__ U,
                      bf16* __restrict__ oA, bf16* __restrict__ oB,
                      bf16* __restrict__ oV, bf16* __restrict__ oU) {
    __shared__ __align__(16) char lds_all[4 * 2048];
    char* lds = lds_all + (threadIdx.x >> 6) * 2048;
    const int lane = threadIdx.x & 63;
    const int l15 = lane & 15, lg = lane >> 4, kb = lg * 8;
    const float *W0, *W1; bf16 *o0, *o1;
    if (blockIdx.y == 0) { W0 = A; W1 = B; o0 = oA; o1 = oB; }
    else                 { W0 = V; W1 = U; o0 = oV; o1 = oU; }

    short8 wf[2][4][2];
#pragma unroll
    for (int m = 0; m < 2; ++m) {
        const float* W = m ? W1 : W0;
#pragma unroll
        for (int t = 0; t < 4; ++t)
#pragma unroll
            for (int f = 0; f < 2; ++f) {
                iv4 q;
#pragma unroll
                for (int j = 0; j < 4; ++j)
                    q[j] = pk2(W[(f * 32 + kb + 2 * j) * HH + t * 16 + l15],
                               W[(f * 32 + kb + 2 * j + 1) * HH + t * 16 + l15]);
                __builtin_memcpy(&wf[m][t][f], &q, 16);
            }
    }
    const int sw = (l15 & 7) << 4;
    int wave = blockIdx.x * 4 + (threadIdx.x >> 6);
    int nw = gridDim.x * 4;
    for (int tile = wave; tile < NN / 16; tile += nw) {
        int row0 = tile * 16;
        iv4 pa, pb;
        if constexpr (FIRST) {
            float2 xv = *(const float2*)(x + 2 * (size_t)(row0 + l15));
#pragma unroll
            for (int j = 0; j < 4; ++j) {
                int k0 = kb + 2 * j;
                pa[j] = pk2(fmaf(xv.x, Wn[k0],     fmaf(xv.y, Wn[HH + k0],     bn[k0])),
                            fmaf(xv.x, Wn[k0 + 1], fmaf(xv.y, Wn[HH + k0 + 1], bn[k0 + 1])));
                int k1 = 32 + kb + 2 * j;
                pb[j] = pk2(fmaf(xv.x, Wn[k1],     fmaf(xv.y, Wn[HH + k1],     bn[k1])),
                            fmaf(xv.x, Wn[k1 + 1], fmaf(xv.y, Wn[HH + k1 + 1], bn[k1 + 1])));
            }
        } else {
            const float* hr = h + (size_t)(row0 + l15) * HH + kb;
            float4 v0 = *(const float4*)(hr);
            float4 v1 = *(const float4*)(hr + 4);
            float4 v2 = *(const float4*)(hr + 32);
            float4 v3 = *(const float4*)(hr + 36);
            pa[0] = pk2(v0.x, v0.y); pa[1] = pk2(v0.z, v0.w);
            pa[2] = pk2(v1.x, v1.y); pa[3] = pk2(v1.z, v1.w);
            pb[0] = pk2(v2.x, v2.y); pb[1] = pk2(v2.z, v2.w);
            pb[2] = pk2(v3.x, v3.y); pb[3] = pk2(v3.z, v3.w);
        }
        short8 af0, af1;
        __builtin_memcpy(&af0, &pa, 16);
        __builtin_memcpy(&af1, &pb, 16);
#pragma unroll
        for (int m = 0; m < 2; ++m) {
            f32x4 acc[4];
#pragma unroll
            for (int t = 0; t < 4; ++t) acc[t] = f32x4{0.f, 0.f, 0.f, 0.f};
#pragma unroll
            for (int t = 0; t < 4; ++t) {
                acc[t] = __builtin_amdgcn_mfma_f32_16x16x32_bf16(af0, wf[m][t][0], acc[t], 0, 0, 0);
                acc[t] = __builtin_amdgcn_mfma_f32_16x16x32_bf16(af1, wf[m][t][1], acc[t], 0, 0, 0);
            }
#pragma unroll
            for (int t = 0; t < 4; ++t)
#pragma unroll
                for (int r = 0; r < 4; ++r) {
                    int row = lg * 4 + r;
                    int ad = (row * 128 + (t * 16 + l15) * 2) ^ ((row & 7) << 4);
                    *(unsigned short*)(lds + ad) =
                        __bfloat16_as_ushort(__float2bfloat16(acc[t][r]));
                }
            int base = l15 * 128 + lg * 32;
            iv4 q0, q1;
            __builtin_memcpy(&q0, lds + ((base) ^ sw), 16);
            __builtin_memcpy(&q1, lds + ((base + 16) ^ sw), 16);
            bf16* out = m ? o1 : o0;
            *(iv4*)(out + (size_t)(row0 + l15) * HH + lg * 16) = q0;
            *(iv4*)(out + (size_t)(row0 + l15) * HH + lg * 16 + 8) = q1;
        }
    }
}

// hybrid static+queue group fetch: 3 static rounds, then atomic tail
#define NEXT_GROUP(g, rep, wq)                                        \
    int g;                                                            \
    if (rep < 3) {                                                    \
        g = blockIdx.x * 4 + (threadIdx.x >> 6) + rep * AGG_WAVES;    \
    } else {                                                          \
        int g0 = 0;                                                   \
        if (lane == 0) g0 = atomicAdd(wq, 1);                         \
        g = NSTATIC + __builtin_amdgcn_readfirstlane(g0);             \
    }                                                                 \
    if (g >= NGRP) break;

// ---------------- layer-0 aggregate: lane = 4 feats x 4 edge-slots ----------------
__global__ __launch_bounds__(256, 2)
void agg0_k(float* __restrict__ h, const bf16* __restrict__ tabs,
            const float* __restrict__ We0, const float* __restrict__ bb0,
            const int* __restrict__ rowptr, const int4* __restrict__ sedge,
            int* __restrict__ wq) {
    __shared__ float fl_all[4][128];
    float* fl = fl_all[threadIdx.x >> 6];
    const int lane = threadIdx.x & 63;
    const int l15 = lane & 15, lg = lane >> 4;
    const int f0 = l15 * 4;
    const size_t nb = (size_t)NN * HH;

    float w0f[4], w1f[4], bbf[4];
#pragma unroll
    for (int q = 0; q < 4; ++q) {
        w0f[q] = We0[f0 + q];
        w1f[q] = We0[HH + f0 + q];
        bbf[q] = bb0[f0 + q];
    }

    struct R0 { uint2 a0[4], hv[4]; };
    for (int rep = 0; ; ++rep) {
        NEXT_GROUP(g, rep, wq)
        int dA = g * DPW;
        int ndst = min(DPW, NN - dA);
        int rpv = rowptr[dA + min(lane, ndst)];

        auto endof = [&](int i2) { return bcasti(rpv, i2 + 1); };
        auto begof = [&](int i2) { return bcasti(rpv, i2); };
        auto ldsed = [&](int i2, int b2) -> int4 {
            int en = endof(i2);
            int idx = b2 + min(l15, en - b2 - 1);
            return sedge[idx];
        };
        auto ldrows = [&](const int4& sd, R0& R) {
#pragma unroll
            for (int r = 0; r < 4; ++r) {
                int s = __shfl(sd.x, lg + 4 * r);
                R.a0[r] = *(const uint2*)(tabs + (size_t)s * HH + f0);
                R.hv[r] = *(const uint2*)(tabs + 6 * nb + (size_t)s * HH + f0);
            }
        };
        auto succ = [&](int& i2, int& b2) {
            if (i2 >= ndst) return;
            if (b2 + 16 < endof(i2)) { b2 += 16; return; }
            i2++;
            while (i2 < ndst && endof(i2) <= begof(i2)) i2++;
            if (i2 < ndst) b2 = begof(i2);
        };

        int iC = 0;
        while (iC < ndst && endof(iC) <= begof(iC)) iC++;
        int bC = (iC < ndst) ? begof(iC) : 0;
        int4 sedC = make_int4(0, 0, 0, 0), sedN = sedC;
        R0 rowsC, rowsN;
        if (iC < ndst) sedC = ldsed(iC, bC);
        int iN = iC, bN = bC;
        if (iC < ndst) succ(iN, bN);
        if (iN < ndst) sedN = ldsed(iN, bN);
        if (iC < ndst) ldrows(sedC, rowsC);

        for (int i = 0; i < ndst; ++i) {
            size_t drow = (size_t)(dA + i) * HH;
            float hu = b2f(tabs[7 * nb + drow + lane]);
            float zb[4];
            {
                uint2 bv = *(const uint2*)(tabs + nb + drow + f0);
                zb[0] = bbf[0] + bflo(bv.x); zb[1] = bbf[1] + bfhi(bv.x);
                zb[2] = bbf[2] + bflo(bv.y); zb[3] = bbf[3] + bfhi(bv.y);
            }
            float nm[4] = {0.f, 0.f, 0.f, 0.f}, dn[4] = {0.f, 0.f, 0.f, 0.f};

            while (iC == i) {
                if (iN < ndst) ldrows(sedN, rowsN);
                int iF = iN, bF = bN;
                succ(iF, bF);
                int4 sedF = sedN;
                if (iF < ndst) sedF = ldsed(iF, bF);

                int cnt = min(endof(i) - bC, 16);
#pragma unroll
                for (int r = 0; r < 4; ++r) {
                    int s = lg + 4 * r;
                    bool valid = s < cnt;
                    float ex = __int_as_float(__shfl(sedC.y, s));
                    float ey = __int_as_float(__shfl(sedC.z, s));
                    uint2 a0 = rowsC.a0[r], hv = rowsC.hv[r];
                    float av[4] = {bflo(a0.x), bfhi(a0.x), bflo(a0.y), bfhi(a0.y)};
                    float hvv[4] = {bflo(hv.x), bfhi(hv.x), bflo(hv.y), bfhi(hv.y)};
#pragma unroll
                    for (int q = 0; q < 4; ++q) {
                        float z = fmaf(ex, w0f[q], fmaf(ey, w1f[q], zb[q])) + av[q];
                        float sg = valid ? 1.f / (1.f + __expf(-z)) : 0.f;
                        nm[q] = fmaf(sg, hvv[q], nm[q]);
                        dn[q] += sg;
                    }
                }
                sedC = sedN; rowsC = rowsN; iC = iN; bC = bN;
                iN = iF; bN = bF; sedN = sedF;
            }

#pragma unroll
            for (int m = 16; m < 64; m <<= 1)
#pragma unroll
                for (int q = 0; q < 4; ++q) {
                    nm[q] += __shfl_xor(nm[q], m);
                    dn[q] += __shfl_xor(dn[q], m);
                }
            if (lg == 0) {
#pragma unroll
                for (int q = 0; q < 4; ++q) {
                    fl[f0 + q] = nm[q];
                    fl[64 + f0 + q] = dn[q];
                }
            }
            float nmv = fl[lane], dnv = fl[64 + lane];
            h[drow + lane] = fmaxf(hu + nmv / (dnv + 1e-6f), 0.f);
        }
    }
}

// ---------------- layers 1/2 aggregate (prescore fused in L2) ----------------
struct Rows { iv4 ra, rb, hva, hvb, b1a, b1b, b2a, b2b; };

template <int LAYER>
__global__ __launch_bounds__(256, 2)
void agg_k(float* __restrict__ h, const bf16* __restrict__ tabs,
           const float* __restrict__ We0, const float* __restrict__ bb0,
           const float* __restrict__ cb, const float* __restrict__ C,
           const int* __restrict__ rowptr, const int4* __restrict__ sedge,
           int* __restrict__ wq, const float* __restrict__ Wp,
           float* __restrict__ ps, float* __restrict__ pd) {
    __shared__ __align__(16) char cfr[LAYER >= 2 ? 16384 : 8192];
    constexpr int WLDS = (LAYER == 1 ? 4096 : 6144);
    __shared__ __align__(16) char lds_all[4 * WLDS];
    char* lds = lds_all + (threadIdx.x >> 6) * WLDS;
    char* Lb1 = lds;
    char* Lb2 = lds + 2048;
    char* Lhv = lds + (LAYER >= 2 ? 4096 : 2048);
    char* Le1 = lds;
    const int lane = threadIdx.x & 63;
    const int l15 = lane & 15, lg = lane >> 4, kb = lg * 8;
    const size_t nb = (size_t)NN * HH;

    {
        int t = threadIdx.x >> 6;
        const float* C1 = C + 1 * HH * HH;
        const float* C2 = C + 2 * HH * HH;
#pragma unroll
        for (int f = 0; f < 2; ++f) {
            iv4 q;
#pragma unroll
            for (int j = 0; j < 4; ++j)
                q[j] = pk2(C1[(f * 32 + kb + 2 * j) * HH + t * 16 + l15],
                           C1[(f * 32 + kb + 2 * j + 1) * HH + t * 16 + l15]);
            *(iv4*)(cfr + ((t * 2 + f) * 64 + lane) * 16) = q;
            if constexpr (LAYER >= 2) {
                iv4 p;
#pragma unroll
                for (int j = 0; j < 4; ++j)
                    p[j] = pk2(C2[(f * 32 + kb + 2 * j) * HH + t * 16 + l15],
                               C2[(f * 32 + kb + 2 * j + 1) * HH + t * 16 + l15]);
                *(iv4*)(cfr + 8192 + ((t * 2 + f) * 64 + lane) * 16) = p;
            }
        }
        __syncthreads();
    }

    float w0a[8], w0b[8], w1a[8], w1b[8], bba[8], bbb[8];
#pragma unroll
    for (int j = 0; j < 8; ++j) {
        w0a[j] = We0[kb + j];        w0b[j] = We0[32 + kb + j];
        w1a[j] = We0[HH + kb + j];   w1b[j] = We0[HH + 32 + kb + j];
        bba[j] = bb0[kb + j];        bbb[j] = bb0[32 + kb + j];
    }
    float cb1t[4], cb2t[4];
#pragma unroll
    for (int t = 0; t < 4; ++t) cb1t[t] = cb[HH + t * 16 + l15];
    if constexpr (LAYER >= 2) {
#pragma unroll
        for (int t = 0; t < 4; ++t) cb2t[t] = cb[2 * HH + t * 16 + l15];
    }
    float wpa = 0.f, wpb = 0.f;
    if constexpr (LAYER >= 2) { wpa = Wp[lane]; wpb = Wp[HH + lane]; }
    const int wlo = (l15 * 128 + lg * 16) ^ ((l15 & 7) << 4);
    const int whi = (l15 * 128 + 64 + lg * 16) ^ ((l15 & 7) << 4);

    for (int rep = 0; ; ++rep) {
        NEXT_GROUP(g, rep, wq)
        int dA = g * DPW;
        int ndst = min(DPW, NN - dA);
        int rpv = rowptr[dA + min(lane, ndst)];

        auto endof = [&](int i2) { return bcasti(rpv, i2 + 1); };
        auto begof = [&](int i2) { return bcasti(rpv, i2); };
        auto ldsed = [&](int i2, int b2) -> int4 {
            int en = endof(i2);
            int idx = b2 + min(l15, en - b2 - 1);
            return sedge[idx];
        };
        auto ldrows = [&](const int4& sd, Rows& R) {
            size_t srow = (size_t)sd.x * HH;
            R.ra  = *(const iv4*)(tabs + srow + kb);
            R.rb  = *(const iv4*)(tabs + srow + 32 + kb);
            R.hva = *(const iv4*)(tabs + 6 * nb + srow + kb);
            R.hvb = *(const iv4*)(tabs + 6 * nb + srow + 32 + kb);
            R.b1a = *(const iv4*)(tabs + 2 * nb + srow + kb);
            R.b1b = *(const iv4*)(tabs + 2 * nb + srow + 32 + kb);
            if constexpr (LAYER >= 2) {
                R.b2a = *(const iv4*)(tabs + 4 * nb + srow + kb);
                R.b2b = *(const iv4*)(tabs + 4 * nb + srow + 32 + kb);
            }
        };
        auto succ = [&](int& i2, int& b2) {
            if (i2 >= ndst) return;
            if (b2 + 16 < endof(i2)) { b2 += 16; return; }
            i2++;
            while (i2 < ndst && endof(i2) <= begof(i2)) i2++;
            if (i2 < ndst) b2 = begof(i2);
        };

        int iC = 0;
        while (iC < ndst && endof(iC) <= begof(iC)) iC++;
        int bC = (iC < ndst) ? begof(iC) : 0;
        int4 sedC = make_int4(0, 0, 0, 0), sedN = sedC;
        Rows rowsC, rowsN;
        if (iC < ndst) sedC = ldsed(iC, bC);
        int iN = iC, bN = bC;
        if (iC < ndst) succ(iN, bN);
        if (iN < ndst) sedN = ldsed(iN, bN);
        if (iC < ndst) ldrows(sedC, rowsC);

        for (int i = 0; i < ndst; ++i) {
            size_t drow = (size_t)(dA + i) * HH;
            float hu = b2f(tabs[7 * nb + drow + lane]);
            float zba[8], zbb[8];
            {
                iv4 ba  = *(const iv4*)(tabs + nb + drow + kb);
                iv4 bbv = *(const iv4*)(tabs + nb + drow + 32 + kb);
#pragma unroll
                for (int q = 0; q < 4; ++q) {
                    zba[2 * q]     = bba[2 * q]     + bflo(ba[q]);
                    zba[2 * q + 1] = bba[2 * q + 1] + bfhi(ba[q]);
                    zbb[2 * q]     = bbb[2 * q]     + bflo(bbv[q]);
                    zbb[2 * q + 1] = bbb[2 * q + 1] + bfhi(bbv[q]);
                }
            }
            float c1d[4], c2d[4];
#pragma unroll
            for (int t = 0; t < 4; ++t)
                c1d[t] = cb1t[t] + b2f(tabs[3 * nb + drow + t * 16 + l15]);
            if constexpr (LAYER >= 2) {
#pragma unroll
                for (int t = 0; t < 4; ++t)
                    c2d[t] = cb2t[t] + b2f(tabs[5 * nb + drow + t * 16 + l15]);
            }

            float nmT[4] = {0.f, 0.f, 0.f, 0.f}, dnT[4] = {0.f, 0.f, 0.f, 0.f};

            while (iC == i) {
                if (iN < ndst) ldrows(sedN, rowsN);
                int iF = iN, bF = bN;
                succ(iF, bF);
                int4 sedF = sedN;
                if (iF < ndst) sedF = ldsed(iF, bF);

                int cnt = min(endof(i) - bC, 16);
                float ex = __int_as_float(sedC.y), ey = __int_as_float(sedC.z);
                float za[8], zc[8];
#pragma unroll
                for (int q = 0; q < 4; ++q) {
                    za[2*q]   = fmaf(ex, w0a[2*q],   fmaf(ey, w1a[2*q],   zba[2*q]))   + bflo(rowsC.ra[q]);
                    za[2*q+1] = fmaf(ex, w0a[2*q+1], fmaf(ey, w1a[2*q+1], zba[2*q+1])) + bfhi(rowsC.ra[q]);
                    zc[2*q]   = fmaf(ex, w0b[2*q],   fmaf(ey, w1b[2*q],   zbb[2*q]))   + bflo(rowsC.rb[q]);
                    zc[2*q+1] = fmaf(ex, w0b[2*q+1], fmaf(ey, w1b[2*q+1], zbb[2*q+1])) + bfhi(rowsC.rb[q]);
                }
                *(iv4*)(Lhv + wlo) = rowsC.hva;  *(iv4*)(Lhv + whi) = rowsC.hvb;
                *(iv4*)(Lb1 + wlo) = rowsC.b1a;  *(iv4*)(Lb1 + whi) = rowsC.b1b;
                if constexpr (LAYER >= 2) {
                    *(iv4*)(Lb2 + wlo) = rowsC.b2a;  *(iv4*)(Lb2 + whi) = rowsC.b2b;
                }
                iv4 pa, pb;
#pragma unroll
                for (int q = 0; q < 4; ++q) {
                    pa[q] = pk2(fmaxf(za[2*q], 0.f), fmaxf(za[2*q+1], 0.f));
                    pb[q] = pk2(fmaxf(zc[2*q], 0.f), fmaxf(zc[2*q+1], 0.f));
                }
                short8 af0, af1;
                __builtin_memcpy(&af0, &pa, 16);
                __builtin_memcpy(&af1, &pb, 16);
                f32x4 acc[4];
#pragma unroll
                for (int t = 0; t < 4; ++t) {
                    f32x4 a;
#pragma unroll
                    for (int r = 0; r < 4; ++r) {
                        int row = lg * 4 + r;
                        int ad = (row * 128 + (t * 16 + l15) * 2) ^ ((row & 7) << 4);
                        a[r] = c1d[t] + b2f(*(const bf16*)(Lb1 + ad));
                    }
                    acc[t] = a;
                }
                __builtin_amdgcn_s_setprio(1);
#pragma unroll
                for (int t = 0; t < 4; ++t) {
                    short8 q0, q1;
                    __builtin_memcpy(&q0, cfr + ((t * 2 + 0) * 64 + lane) * 16, 16);
                    __builtin_memcpy(&q1, cfr + ((t * 2 + 1) * 64 + lane) * 16, 16);
                    acc[t] = __builtin_amdgcn_mfma_f32_16x16x32_bf16(af0, q0, acc[t], 0, 0, 0);
                    acc[t] = __builtin_amdgcn_mfma_f32_16x16x32_bf16(af1, q1, acc[t], 0, 0, 0);
                }
                __builtin_amdgcn_s_setprio(0);
                if constexpr (LAYER >= 2) {
#pragma unroll
                    for (int t = 0; t < 4; ++t)
#pragma unroll
                        for (int r = 0; r < 4; ++r) {
                            int row = lg * 4 + r;
                            int ad = (row * 128 + (t * 16 + l15) * 2) ^ ((row & 7) << 4);
                            *(unsigned short*)(Le1 + ad) =
                                __bfloat16_as_ushort(__float2bfloat16(fmaxf(acc[t][r], 0.f)));
                        }
                    short8 ag0, ag1;
                    __builtin_memcpy(&ag0, Le1 + ((l15 * 128 + kb * 2) ^ ((l15 & 7) << 4)), 16);
                    __builtin_memcpy(&ag1, Le1 + ((l15 * 128 + 64 + kb * 2) ^ ((l15 & 7) << 4)), 16);
#pragma unroll
                    for (int t = 0; t < 4; ++t) {
                        f32x4 a;
#pragma unroll
                        for (int r = 0; r < 4; ++r) {
                            int row = lg * 4 + r;
                            int ad = (row * 128 + (t * 16 + l15) * 2) ^ ((row & 7) << 4);
                            a[r] = c2d[t] + b2f(*(const bf16*)(Lb2 + ad));
                        }
                        acc[t] = a;
                    }
                    __builtin_amdgcn_s_setprio(1);
#pragma unroll
                    for (int t = 0; t < 4; ++t) {
                        short8 q0, q1;
                        __builtin_memcpy(&q0, cfr + 8192 + ((t * 2 + 0) * 64 + lane) * 16, 16);
                        __builtin_memcpy(&q1, cfr + 8192 + ((t * 2 + 1) * 64 + lane) * 16, 16);
                        acc[t] = __builtin_amdgcn_mfma_f32_16x16x32_bf16(ag0, q0, acc[t], 0, 0, 0);
                        acc[t] = __builtin_amdgcn_mfma_f32_16x16x32_bf16(ag1, q1, acc[t], 0, 0, 0);
                    }
                    __builtin_amdgcn_s_setprio(0);
                }
#pragma unroll
                for (int r = 0; r < 4; ++r) {
                    int row = lg * 4 + r;
                    bool valid = row < cnt;
#pragma unroll
                    for (int t = 0; t < 4; ++t) {
                        float sg = valid ? 1.f / (1.f + __expf(-acc[t][r])) : 0.f;
                        int ad = (row * 128 + (t * 16 + l15) * 2) ^ ((row & 7) << 4);
                        nmT[t] = fmaf(sg, b2f(*(const bf16*)(Lhv + ad)), nmT[t]);
                        dnT[t] += sg;
                    }
                }
                sedC = sedN; rowsC = rowsN; iC = iN; bC = bN;
                iN = iF; bN = bF; sedN = sedF;
            }

            float* fl = (float*)Le1;
#pragma unroll
            for (int m = 16; m < 64; m <<= 1)
#pragma unroll
                for (int t = 0; t < 4; ++t) {
                    nmT[t] += __shfl_xor(nmT[t], m);
                    dnT[t] += __shfl_xor(dnT[t], m);
                }
            if (lg == 0) {
#pragma unroll
                for (int t = 0; t < 4; ++t) {
                    fl[t * 16 + l15]      = nmT[t];
                    fl[64 + t * 16 + l15] = dnT[t];
                }
            }
            float nmv = fl[lane], dnv = fl[64 + lane];
            float hval = fmaxf(hu + nmv / (dnv + 1e-6f), 0.f);
            if constexpr (LAYER < 2) {
                h[drow + lane] = hval;
            } else {
                // fused prescore: ps[d] = h[d]@Wp[:64], pd[d] = h[d]@Wp[64:]
                float a = hval * wpa, b = hval * wpb;
#pragma unroll
                for (int m = 32; m; m >>= 1) {
                    a += __shfl_xor(a, m);
                    b += __shfl_xor(b, m);
                }
                if (lane == 0) { ps[dA + i] = a; pd[dA + i] = b; }
            }
        }
    }
}

// ---------------- scoring ----------------
__global__ void score2_k(const float* __restrict__ ps, const float* __restrict__ pd,
                         const float* __restrict__ bp, const int* __restrict__ ss,
                         const int* __restrict__ ds, float* __restrict__ out) {
    int i = blockIdx.x * blockDim.x + threadIdx.x;
    if (i < NS) out[i] = ps[ss[i]] + pd[ds[i]] + bp[0];
}

extern "C" void kernel_launch(void* const* d_in, const int* in_sizes, int n_in,
                              void* d_out, int out_size, void* d_ws, size_t ws_size,
                              hipStream_t stream) {
    const float* x  = (const float*)d_in[0];
    const float* e0 = (const float*)d_in[1];
    const float* Wn = (const float*)d_in[2];
    const float* bn = (const float*)d_in[3];
    const float* We = (const float*)d_in[4];
    const float* be = (const float*)d_in[5];
    const float* A  = (const float*)d_in[6];
    const float* B  = (const float*)d_in[7];
    const float* C  = (const float*)d_in[8];
    const float* cb = (const float*)d_in[9];
    const float* U  = (const float*)d_in[10];
    const float* V  = (const float*)d_in[11];
    const float* Wp = (const float*)d_in[12];
    const float* bp = (const float*)d_in[13];
    const int* src  = (const int*)d_in[14];
    const int* dst  = (const int*)d_in[15];
    const int* ss   = (const int*)d_in[16];
    const int* ds   = (const int*)d_in[17];

    char* ws = (char*)d_ws;
    size_t nb = (size_t)NN * HH;
    float* h      = (float*)ws;                    // 25.6 MB
    bf16*  tabs   = (bf16*)(ws + nb * 4);          // 8 x 12.8 MB  [A0,B0,A1,B1,A2,B2,hV,hU]
    int4*  sedge  = (int4*)(tabs + 8 * nb);        // 25.6 MB
    int*   cnt    = (int*)(sedge + NE);
    int*   rowptr = cnt + NN;
    int*   cursor = rowptr + (NN + 1);
    int*   bsum   = cursor + NN;
    int*   bofs   = bsum + SCAN_G;
    float* We0    = (float*)(bofs + SCAN_G);
    float* bb0    = We0 + 2 * HH;
    float* ps     = bb0 + HH;
    float* pd     = ps + NN;
    int*   wq     = (int*)(pd + NN);               // 4 queue counters

    prep_k<<<1, 64, 0, stream>>>(We, be, C, cb, We0, bb0);

    zero_int_k<<<(NN + 255) / 256, 256, 0, stream>>>(cnt, NN);
    zero_int_k<<<1, 64, 0, stream>>>(wq, 4);
    hist_k<<<(NE + 255) / 256, 256, 0, stream>>>(dst, cnt);
    scan1_k<<<SCAN_G, SCAN_B, 0, stream>>>(cnt, rowptr, bsum);
    scan2_k<<<1, 64, 0, stream>>>(bsum, bofs);
    scan3_k<<<SCAN_G, SCAN_B, 0, stream>>>(rowptr, cursor, bofs);
    scatter_k<<<(NE + 255) / 256, 256, 0, stream>>>(dst, src, (const float2*)e0,
                                                    cursor, sedge);

    for (int l = 0; l < 3; ++l) {
        if (l == 0)
            transform_mfma_k<true><<<dim3(512, 2), 256, 0, stream>>>(
                h, x, Wn, bn,
                A + (size_t)l * HH * HH, B + (size_t)l * HH * HH,
                V + (size_t)l * HH * HH, U + (size_t)l * HH * HH,
                tabs + 2 * (size_t)l * nb, tabs + (2 * (size_t)l + 1) * nb,
                tabs + 6 * nb, tabs + 7 * nb);
        else
            transform_mfma_k<false><<<dim3(512, 2), 256, 0, stream>>>(
                h, x, Wn, bn,
                A + (size_t)l * HH * HH, B + (size_t)l * HH * HH,
                V + (size_t)l * HH * HH, U + (size_t)l * HH * HH,
                tabs + 2 * (size_t)l * nb, tabs + (2 * (size_t)l + 1) * nb,
                tabs + 6 * nb, tabs + 7 * nb);
        if (l == 0)
            agg0_k<<<AGG_BLOCKS, 256, 0, stream>>>(h, tabs, We0, bb0, rowptr, sedge,
                                                   wq + 0);
        else if (l == 1)
            agg_k<1><<<AGG_BLOCKS, 256, 0, stream>>>(h, tabs, We0, bb0, cb, C, rowptr,
                                                     sedge, wq + 1, Wp, ps, pd);
        else
            agg_k<2><<<AGG_BLOCKS, 256, 0, stream>>>(h, tabs, We0, bb0, cb, C, rowptr,
                                                     sedge, wq + 2, Wp, ps, pd);
    }

    score2_k<<<(NS + 255) / 256, 256, 0, stream>>>(ps, pd, bp, ss, ds, (float*)d_out);
}